// Round 1
// baseline (6276.345 us; speedup 1.0000x reference)
//
#include <hip/hip_runtime.h>
#include <hip/hip_bf16.h>

#define N_NODES  20000
#define N_EDGES  160000
#define N_TOT_E  180000   // edges + self loops
#define N_GRAPHS 64
#define EMBED_DIM 32
#define IN_GNN   36
#define H1       2048
#define H2       1024

// ---------------- small utility kernels ----------------

__global__ void fill_ones(float* p, int n) {
    int i = blockIdx.x * 256 + threadIdx.x;
    if (i < n) p[i] = 1.0f;
}

__global__ void deg_accum(const int* __restrict__ ei, float* deg) {
    int e = blockIdx.x * 256 + threadIdx.x;
    if (e < N_EDGES) atomicAdd(&deg[ei[N_EDGES + e]], 1.0f);
}

__global__ void deg_to_dinv(float* d) {
    int i = blockIdx.x * 256 + threadIdx.x;
    if (i < N_NODES) d[i] = rsqrtf(d[i]);   // deg >= 1 always (self loop)
}

__global__ void build_xfeat(const int* __restrict__ ids, const float* __restrict__ other,
                            const float* __restrict__ emb, float* __restrict__ xf) {
    int idx = blockIdx.x * 256 + threadIdx.x;   // node*36 + d
    if (idx >= N_NODES * IN_GNN) return;
    int i = idx / IN_GNN;
    int d = idx - i * IN_GNN;
    float v = (d < EMBED_DIM) ? emb[(size_t)ids[i] * EMBED_DIM + d]
                              : other[i * 4 + (d - EMBED_DIM)];
    xf[idx] = v;
}

// ---------------- layer-1 aggregation (36-dim) ----------------

__global__ void agg_edges_36(const int* __restrict__ ei, const float* __restrict__ dinv,
                             const float* __restrict__ xf, float* __restrict__ agg) {
    int idx = blockIdx.x * 256 + threadIdx.x;   // (edge, dim)
    if (idx >= N_TOT_E * IN_GNN) return;
    int e = idx / IN_GNN;
    int d = idx - e * IN_GNN;
    int s, t;
    if (e < N_EDGES) { s = ei[e]; t = ei[N_EDGES + e]; }
    else             { s = t = e - N_EDGES; }
    float nrm = dinv[s] * dinv[t];
    atomicAdd(&agg[t * IN_GNN + d], xf[s * IN_GNN + d] * nrm);
}

// ---------------- GEMM1: agg1[20000,36] @ W1[36,2048] + b1, relu -> x1 ----------------
// block: 256 threads = 256 cols, 32 rows per block
__global__ __launch_bounds__(256) void gemm1_relu(const float* __restrict__ A,
                                                  const float* __restrict__ W,
                                                  const float* __restrict__ b,
                                                  float* __restrict__ X) {
    __shared__ __align__(16) float As[32][IN_GNN];   // 32x36 f32
    int rb = blockIdx.y * 32;
    int n  = blockIdx.x * 256 + threadIdx.x;
    for (int t = threadIdx.x; t < 32 * IN_GNN; t += 256) {
        int r = t / IN_GNN, k = t - r * IN_GNN;
        int gr = rb + r;
        As[r][k] = (gr < N_NODES) ? A[gr * IN_GNN + k] : 0.0f;
    }
    __syncthreads();
    float acc[32];
#pragma unroll
    for (int r = 0; r < 32; r++) acc[r] = 0.0f;
#pragma unroll
    for (int k = 0; k < IN_GNN; k += 4) {
        float w0 = W[(size_t)(k + 0) * H1 + n];
        float w1 = W[(size_t)(k + 1) * H1 + n];
        float w2 = W[(size_t)(k + 2) * H1 + n];
        float w3 = W[(size_t)(k + 3) * H1 + n];
#pragma unroll
        for (int r = 0; r < 32; r++) {
            float4 a = *(const float4*)&As[r][k];
            acc[r] += a.x * w0 + a.y * w1 + a.z * w2 + a.w * w3;
        }
    }
    float bias = b[n];
    for (int r = 0; r < 32; r++) {
        int gr = rb + r;
        if (gr < N_NODES) X[(size_t)gr * H1 + n] = fmaxf(acc[r] + bias, 0.0f);
    }
}

// ---------------- GEMM2: x1[20000,2048] @ W2[2048,1024] -> xw2 ----------------
#define BM 128
#define BN 128
#define BK 16
__global__ __launch_bounds__(256) void gemm2_f32(const float* __restrict__ A,
                                                 const float* __restrict__ B,
                                                 float* __restrict__ C) {
    __shared__ __align__(16) float As[BK][BM + 4];   // k-major (transposed), padded
    __shared__ __align__(16) float Bs[BK][BN];
    const int K = H1;            // 2048
    int tid = threadIdx.x;
    int tx = tid & 15, ty = tid >> 4;          // 16x16 thread grid, 8x8 micro-tile
    int row0 = blockIdx.y * BM;
    int col0 = blockIdx.x * BN;

    int ar = tid >> 2;           // 0..63 (two halves: +0, +64)
    int ak = (tid & 3) * 4;      // k offset within BK
    int br = tid >> 5;           // 0..7 (two halves: +0, +8)
    int bc = (tid & 31) * 4;

    float acc[8][8] = {};

    for (int k0 = 0; k0 < K; k0 += BK) {
#pragma unroll
        for (int h = 0; h < 2; h++) {
            int r  = ar + h * 64;
            int gr = row0 + r;
            float4 v = make_float4(0.f, 0.f, 0.f, 0.f);
            if (gr < N_NODES) v = *(const float4*)&A[(size_t)gr * K + k0 + ak];
            As[ak + 0][r] = v.x; As[ak + 1][r] = v.y;
            As[ak + 2][r] = v.z; As[ak + 3][r] = v.w;
        }
#pragma unroll
        for (int h = 0; h < 2; h++) {
            int r = br + h * 8;
            *(float4*)&Bs[r][bc] = *(const float4*)&B[(size_t)(k0 + r) * H2 + col0 + bc];
        }
        __syncthreads();
#pragma unroll
        for (int kk = 0; kk < BK; kk++) {
            float a[8], bb[8];
            *(float4*)&a[0]  = *(const float4*)&As[kk][ty * 8];
            *(float4*)&a[4]  = *(const float4*)&As[kk][ty * 8 + 4];
            *(float4*)&bb[0] = *(const float4*)&Bs[kk][tx * 8];
            *(float4*)&bb[4] = *(const float4*)&Bs[kk][tx * 8 + 4];
#pragma unroll
            for (int i = 0; i < 8; i++)
#pragma unroll
                for (int j = 0; j < 8; j++)
                    acc[i][j] += a[i] * bb[j];
        }
        __syncthreads();
    }
#pragma unroll
    for (int i = 0; i < 8; i++) {
        int gr = row0 + ty * 8 + i;
        if (gr < N_NODES) {
            *(float4*)&C[(size_t)gr * H2 + col0 + tx * 8 + 0] = *(const float4*)&acc[i][0];
            *(float4*)&C[(size_t)gr * H2 + col0 + tx * 8 + 4] = *(const float4*)&acc[i][4];
        }
    }
}

// ---------------- layer-2 aggregation (1024-dim) ----------------
__global__ __launch_bounds__(256) void agg_edges_1024(const int* __restrict__ ei,
                                                      const float* __restrict__ dinv,
                                                      const float* __restrict__ xw,
                                                      float* __restrict__ agg) {
    int e = blockIdx.x;
    int s, t;
    if (e < N_EDGES) { s = ei[e]; t = ei[N_EDGES + e]; }
    else             { s = t = e - N_EDGES; }
    float nrm = dinv[s] * dinv[t];
    const float4* src = (const float4*)&xw[(size_t)s * H2];
    float* dst = &agg[(size_t)t * H2];
    int d = threadIdx.x;             // 256 threads x float4 = 1024 dims
    float4 v = src[d];
    atomicAdd(&dst[d * 4 + 0], v.x * nrm);
    atomicAdd(&dst[d * 4 + 1], v.y * nrm);
    atomicAdd(&dst[d * 4 + 2], v.z * nrm);
    atomicAdd(&dst[d * 4 + 3], v.w * nrm);
}

__global__ void bias_relu_1024(float* __restrict__ x, const float* __restrict__ b) {
    int idx = blockIdx.x * 256 + threadIdx.x;
    if (idx < N_NODES * H2) {
        int d = idx & (H2 - 1);
        x[idx] = fmaxf(x[idx] + b[d], 0.0f);
    }
}

// ---------------- pooling ----------------
__global__ void cnt_accum(const int* __restrict__ batch, float* cnt) {
    int i = blockIdx.x * 256 + threadIdx.x;
    if (i < N_NODES) atomicAdd(&cnt[batch[i]], 1.0f);
}

__global__ void pool_accum(const int* __restrict__ batch, const float* __restrict__ x2,
                           float* __restrict__ pooled) {
    int d  = blockIdx.x * 256 + threadIdx.x;   // 0..1023
    int i0 = blockIdx.y * 64;
    float acc = 0.0f;
    int gprev = -1;
    for (int i = 0; i < 64; i++) {
        int node = i0 + i;
        if (node >= N_NODES) break;
        int g = batch[node];
        if (g != gprev) {
            if (gprev >= 0) atomicAdd(&pooled[gprev * H2 + d], acc);
            acc = 0.0f; gprev = g;
        }
        acc += x2[(size_t)node * H2 + d];
    }
    if (gprev >= 0) atomicAdd(&pooled[gprev * H2 + d], acc);
}

__global__ void pool_norm(float* pooled, const float* cnt) {
    int idx = blockIdx.x * 256 + threadIdx.x;
    if (idx < N_GRAPHS * H2) {
        int g = idx >> 10;
        pooled[idx] /= fmaxf(cnt[g], 1.0f);
    }
}

// ---------------- MLP head ----------------
// partial GEMM: Out[m0..m0+15][n] += sum over 256-k-slice of In[m][k]*W[k][n]
__global__ __launch_bounds__(256) void head_gemm(const float* __restrict__ In,
                                                 const float* __restrict__ W,
                                                 float* __restrict__ Out, int K, int N) {
    __shared__ __align__(16) float As[16][256];
    int n  = blockIdx.x * 256 + threadIdx.x;
    int m0 = blockIdx.y * 16;
    int k0 = blockIdx.z * 256;
    for (int t = threadIdx.x; t < 16 * 256; t += 256) {
        int r = t >> 8, k = t & 255;
        As[r][k] = In[(size_t)(m0 + r) * K + k0 + k];
    }
    __syncthreads();
    float acc[16] = {};
    for (int k = 0; k < 256; k += 4) {
        float w0 = W[(size_t)(k0 + k + 0) * N + n];
        float w1 = W[(size_t)(k0 + k + 1) * N + n];
        float w2 = W[(size_t)(k0 + k + 2) * N + n];
        float w3 = W[(size_t)(k0 + k + 3) * N + n];
#pragma unroll
        for (int r = 0; r < 16; r++) {
            float4 a = *(const float4*)&As[r][k];
            acc[r] += a.x * w0 + a.y * w1 + a.z * w2 + a.w * w3;
        }
    }
    for (int r = 0; r < 16; r++)
        atomicAdd(&Out[(size_t)(m0 + r) * N + n], acc[r]);
}

__global__ void bias_relu_MN(float* __restrict__ x, const float* __restrict__ b,
                             int N, int total) {
    int idx = blockIdx.x * 256 + threadIdx.x;
    if (idx < total) {
        int d = idx & (N - 1);    // N is a power of two
        x[idx] = fmaxf(x[idx] + b[d], 0.0f);
    }
}

__global__ void head3(const float* __restrict__ h2, const float* __restrict__ oW,
                      const float* __restrict__ ob, float* __restrict__ out) {
    int tid = threadIdx.x;          // 128 threads: m = tid/2, c = tid&1
    if (tid >= 128) return;
    int m = tid >> 1, c = tid & 1;
    float acc = 0.0f;
    for (int k = 0; k < 512; k++) acc += h2[m * 512 + k] * oW[k * 2 + c];
    out[tid] = acc + ob[c];
}

// ---------------- host ----------------
extern "C" void kernel_launch(void* const* d_in, const int* in_sizes, int n_in,
                              void* d_out, int out_size, void* d_ws, size_t ws_size,
                              hipStream_t stream) {
    const int*   ids   = (const int*)d_in[0];
    const float* other = (const float*)d_in[1];
    const int*   ei    = (const int*)d_in[2];
    const int*   batch = (const int*)d_in[3];
    const float* emb   = (const float*)d_in[4];
    const float* W1    = (const float*)d_in[5];
    const float* b1    = (const float*)d_in[6];
    const float* W2    = (const float*)d_in[7];
    const float* b2    = (const float*)d_in[8];
    const float* hW1   = (const float*)d_in[9];
    const float* hb1   = (const float*)d_in[10];
    const float* hW2   = (const float*)d_in[11];
    const float* hb2   = (const float*)d_in[12];
    const float* oW    = (const float*)d_in[13];
    const float* ob    = (const float*)d_in[14];
    float* out = (float*)d_out;

    char* ws = (char*)d_ws;
    size_t off = 0;
    auto alloc = [&](size_t bytes) {
        size_t p = (off + 255) & ~(size_t)255;
        off = p + bytes;
        return p;
    };
    size_t o_dinv = alloc((size_t)N_NODES * 4);
    size_t o_xf   = alloc((size_t)N_NODES * IN_GNN * 4);
    size_t o_agg1 = alloc((size_t)N_NODES * IN_GNN * 4);
    size_t o_x1   = alloc((size_t)N_NODES * H1 * 4);     // later reused as x2
    size_t o_xw2  = alloc((size_t)N_NODES * H2 * 4);
    size_t o_pool = alloc((size_t)N_GRAPHS * H2 * 4);
    size_t o_cnt  = alloc((size_t)N_GRAPHS * 4);
    size_t o_h1   = alloc((size_t)N_GRAPHS * 1024 * 4);
    size_t o_h2   = alloc((size_t)N_GRAPHS * 512 * 4);

    float* dinv = (float*)(ws + o_dinv);
    float* xf   = (float*)(ws + o_xf);
    float* agg1 = (float*)(ws + o_agg1);
    float* x1   = (float*)(ws + o_x1);
    float* xw2  = (float*)(ws + o_xw2);
    float* x2   = (float*)(ws + o_x1);    // alias: x1 dead after gemm2
    float* pooled = (float*)(ws + o_pool);
    float* cnt  = (float*)(ws + o_cnt);
    float* h1   = (float*)(ws + o_h1);
    float* h2   = (float*)(ws + o_h2);

    // degree + dinv
    fill_ones<<<(N_NODES + 255) / 256, 256, 0, stream>>>(dinv, N_NODES);
    deg_accum<<<(N_EDGES + 255) / 256, 256, 0, stream>>>(ei, dinv);
    deg_to_dinv<<<(N_NODES + 255) / 256, 256, 0, stream>>>(dinv);

    // node features
    build_xfeat<<<(N_NODES * IN_GNN + 255) / 256, 256, 0, stream>>>(ids, other, emb, xf);

    // layer 1: aggregate(36) then GEMM
    hipMemsetAsync(agg1, 0, (size_t)N_NODES * IN_GNN * 4, stream);
    agg_edges_36<<<(N_TOT_E * IN_GNN + 255) / 256, 256, 0, stream>>>(ei, dinv, xf, agg1);
    gemm1_relu<<<dim3(H1 / 256, (N_NODES + 31) / 32), 256, 0, stream>>>(agg1, W1, b1, x1);

    // layer 2: GEMM then aggregate(1024)
    gemm2_f32<<<dim3(H2 / BN, (N_NODES + BM - 1) / BM), 256, 0, stream>>>(x1, W2, xw2);
    hipMemsetAsync(x2, 0, (size_t)N_NODES * H2 * 4, stream);   // x1 is dead now
    agg_edges_1024<<<N_TOT_E, 256, 0, stream>>>(ei, dinv, xw2, x2);
    bias_relu_1024<<<(N_NODES * H2 + 255) / 256, 256, 0, stream>>>(x2, b2);

    // mean pool
    hipMemsetAsync(pooled, 0, (size_t)N_GRAPHS * H2 * 4, stream);
    hipMemsetAsync(cnt, 0, (size_t)N_GRAPHS * 4, stream);
    cnt_accum<<<(N_NODES + 255) / 256, 256, 0, stream>>>(batch, cnt);
    pool_accum<<<dim3(H2 / 256, (N_NODES + 63) / 64), 256, 0, stream>>>(batch, x2, pooled);
    pool_norm<<<(N_GRAPHS * H2 + 255) / 256, 256, 0, stream>>>(pooled, cnt);

    // head
    hipMemsetAsync(h1, 0, (size_t)N_GRAPHS * 1024 * 4, stream);
    head_gemm<<<dim3(1024 / 256, 4, 1024 / 256), 256, 0, stream>>>(pooled, hW1, h1, 1024, 1024);
    bias_relu_MN<<<(N_GRAPHS * 1024 + 255) / 256, 256, 0, stream>>>(h1, hb1, 1024, N_GRAPHS * 1024);

    hipMemsetAsync(h2, 0, (size_t)N_GRAPHS * 512 * 4, stream);
    head_gemm<<<dim3(512 / 256, 4, 1024 / 256), 256, 0, stream>>>(h1, hW2, h2, 1024, 512);
    bias_relu_MN<<<(N_GRAPHS * 512 + 255) / 256, 256, 0, stream>>>(h2, hb2, 512, N_GRAPHS * 512);

    head3<<<1, 128, 0, stream>>>(h2, oW, ob, out);
}

// Round 2
// 3650.314 us; speedup vs baseline: 1.7194x; 1.7194x over previous
//
#include <hip/hip_runtime.h>
#include <hip/hip_bf16.h>

#define N_NODES  20000
#define N_EDGES  160000
#define N_TOT_E  180000   // edges + self loops
#define N_GRAPHS 64
#define EMBED_DIM 32
#define IN_GNN   36
#define H1       2048
#define H2       1024

// ---------------- small utility kernels ----------------

__global__ void fill_f32(float* p, float v, int n) {
    int i = blockIdx.x * 256 + threadIdx.x;
    if (i < n) p[i] = v;
}

__global__ void fill_i32(int* p, int v, int n) {
    int i = blockIdx.x * 256 + threadIdx.x;
    if (i < n) p[i] = v;
}

__global__ void deg_accum(const int* __restrict__ ei, float* deg, int* indeg) {
    int e = blockIdx.x * 256 + threadIdx.x;
    if (e < N_EDGES) {
        int t = ei[N_EDGES + e];
        atomicAdd(&deg[t], 1.0f);
        atomicAdd(&indeg[t], 1);
    }
}

__global__ void deg_to_dinv(float* d) {
    int i = blockIdx.x * 256 + threadIdx.x;
    if (i < N_NODES) d[i] = rsqrtf(d[i]);   // deg >= 1 always (self loop)
}

__global__ void build_xfeat(const int* __restrict__ ids, const float* __restrict__ other,
                            const float* __restrict__ emb, float* __restrict__ xf) {
    int idx = blockIdx.x * 256 + threadIdx.x;   // node*36 + d
    if (idx >= N_NODES * IN_GNN) return;
    int i = idx / IN_GNN;
    int d = idx - i * IN_GNN;
    float v = (d < EMBED_DIM) ? emb[(size_t)ids[i] * EMBED_DIM + d]
                              : other[i * 4 + (d - EMBED_DIM)];
    xf[idx] = v;
}

// ---------------- CSR build ----------------
// single-workgroup exclusive scan of indeg[N_NODES] -> off[N_NODES+1], cursor copy
__global__ __launch_bounds__(1024) void scan_offsets(const int* __restrict__ indeg,
                                                     int* __restrict__ off,
                                                     int* __restrict__ cursor) {
    __shared__ int buf[1024];
    __shared__ int base_s;
    int tid = threadIdx.x;
    if (tid == 0) base_s = 0;
    __syncthreads();
    for (int start = 0; start < N_NODES; start += 1024) {
        int i = start + tid;
        int v = (i < N_NODES) ? indeg[i] : 0;
        buf[tid] = v;
        __syncthreads();
        for (int s = 1; s < 1024; s <<= 1) {
            int t = (tid >= s) ? buf[tid - s] : 0;
            __syncthreads();
            buf[tid] += t;
            __syncthreads();
        }
        int incl = buf[tid];
        int excl = incl - v;
        int base = base_s;
        if (i < N_NODES) {
            int o = base + excl;
            off[i] = o;
            cursor[i] = o;
        }
        __syncthreads();
        if (tid == 1023) base_s = base + incl;
        __syncthreads();
    }
    if (tid == 0) off[N_NODES] = N_TOT_E;
}

__global__ void csr_fill(const int* __restrict__ ei, const float* __restrict__ dinv,
                         int* __restrict__ cursor,
                         int* __restrict__ csr_src, float* __restrict__ csr_nrm) {
    int e = blockIdx.x * 256 + threadIdx.x;
    if (e >= N_TOT_E) return;
    int s, t;
    if (e < N_EDGES) { s = ei[e]; t = ei[N_EDGES + e]; }
    else             { s = t = e - N_EDGES; }
    int pos = atomicAdd(&cursor[t], 1);
    csr_src[pos] = s;
    csr_nrm[pos] = dinv[s] * dinv[t];
}

// ---------------- layer-1 aggregation via CSR gather (36-dim) ----------------
__global__ void agg_csr_36(const int* __restrict__ off, const int* __restrict__ csr_src,
                           const float* __restrict__ csr_nrm,
                           const float* __restrict__ xf, float* __restrict__ agg) {
    int idx = blockIdx.x * 256 + threadIdx.x;   // node*36 + d
    if (idx >= N_NODES * IN_GNN) return;
    int node = idx / IN_GNN;
    int d = idx - node * IN_GNN;
    int p0 = off[node], p1 = off[node + 1];
    float acc = 0.0f;
    for (int p = p0; p < p1; p++)
        acc += xf[csr_src[p] * IN_GNN + d] * csr_nrm[p];
    agg[idx] = acc;
}

// ---------------- GEMM1: agg1[20000,36] @ W1[36,2048] + b1, relu -> x1 ----------------
__global__ __launch_bounds__(256) void gemm1_relu(const float* __restrict__ A,
                                                  const float* __restrict__ W,
                                                  const float* __restrict__ b,
                                                  float* __restrict__ X) {
    __shared__ __align__(16) float As[32][IN_GNN];   // 32x36 f32
    int rb = blockIdx.y * 32;
    int n  = blockIdx.x * 256 + threadIdx.x;
    for (int t = threadIdx.x; t < 32 * IN_GNN; t += 256) {
        int r = t / IN_GNN, k = t - r * IN_GNN;
        int gr = rb + r;
        As[r][k] = (gr < N_NODES) ? A[gr * IN_GNN + k] : 0.0f;
    }
    __syncthreads();
    float acc[32];
#pragma unroll
    for (int r = 0; r < 32; r++) acc[r] = 0.0f;
#pragma unroll
    for (int k = 0; k < IN_GNN; k += 4) {
        float w0 = W[(size_t)(k + 0) * H1 + n];
        float w1 = W[(size_t)(k + 1) * H1 + n];
        float w2 = W[(size_t)(k + 2) * H1 + n];
        float w3 = W[(size_t)(k + 3) * H1 + n];
#pragma unroll
        for (int r = 0; r < 32; r++) {
            float4 a = *(const float4*)&As[r][k];
            acc[r] += a.x * w0 + a.y * w1 + a.z * w2 + a.w * w3;
        }
    }
    float bias = b[n];
    for (int r = 0; r < 32; r++) {
        int gr = rb + r;
        if (gr < N_NODES) X[(size_t)gr * H1 + n] = fmaxf(acc[r] + bias, 0.0f);
    }
}

// ---------------- GEMM2: x1[20000,2048] @ W2[2048,1024] -> xw2 ----------------
#define BM 128
#define BN 128
#define BK 16
__global__ __launch_bounds__(256) void gemm2_f32(const float* __restrict__ A,
                                                 const float* __restrict__ B,
                                                 float* __restrict__ C) {
    __shared__ __align__(16) float As[BK][BM + 4];   // k-major (transposed), padded
    __shared__ __align__(16) float Bs[BK][BN];
    const int K = H1;            // 2048
    int tid = threadIdx.x;
    int tx = tid & 15, ty = tid >> 4;          // 16x16 thread grid, 8x8 micro-tile
    int row0 = blockIdx.y * BM;
    int col0 = blockIdx.x * BN;

    int ar = tid >> 2;           // 0..63 (two halves: +0, +64)
    int ak = (tid & 3) * 4;      // k offset within BK
    int br = tid >> 5;           // 0..7 (two halves: +0, +8)
    int bc = (tid & 31) * 4;

    float acc[8][8] = {};

    for (int k0 = 0; k0 < K; k0 += BK) {
#pragma unroll
        for (int h = 0; h < 2; h++) {
            int r  = ar + h * 64;
            int gr = row0 + r;
            float4 v = make_float4(0.f, 0.f, 0.f, 0.f);
            if (gr < N_NODES) v = *(const float4*)&A[(size_t)gr * K + k0 + ak];
            As[ak + 0][r] = v.x; As[ak + 1][r] = v.y;
            As[ak + 2][r] = v.z; As[ak + 3][r] = v.w;
        }
#pragma unroll
        for (int h = 0; h < 2; h++) {
            int r = br + h * 8;
            *(float4*)&Bs[r][bc] = *(const float4*)&B[(size_t)(k0 + r) * H2 + col0 + bc];
        }
        __syncthreads();
#pragma unroll
        for (int kk = 0; kk < BK; kk++) {
            float a[8], bb[8];
            *(float4*)&a[0]  = *(const float4*)&As[kk][ty * 8];
            *(float4*)&a[4]  = *(const float4*)&As[kk][ty * 8 + 4];
            *(float4*)&bb[0] = *(const float4*)&Bs[kk][tx * 8];
            *(float4*)&bb[4] = *(const float4*)&Bs[kk][tx * 8 + 4];
#pragma unroll
            for (int i = 0; i < 8; i++)
#pragma unroll
                for (int j = 0; j < 8; j++)
                    acc[i][j] += a[i] * bb[j];
        }
        __syncthreads();
    }
#pragma unroll
    for (int i = 0; i < 8; i++) {
        int gr = row0 + ty * 8 + i;
        if (gr < N_NODES) {
            *(float4*)&C[(size_t)gr * H2 + col0 + tx * 8 + 0] = *(const float4*)&acc[i][0];
            *(float4*)&C[(size_t)gr * H2 + col0 + tx * 8 + 4] = *(const float4*)&acc[i][4];
        }
    }
}

// ---------------- layer-2 aggregation via CSR gather (1024-dim), bias+relu fused ----
__global__ __launch_bounds__(256) void agg_csr_1024(const int* __restrict__ off,
                                                    const int* __restrict__ csr_src,
                                                    const float* __restrict__ csr_nrm,
                                                    const float* __restrict__ xw,
                                                    const float* __restrict__ b,
                                                    float* __restrict__ x2) {
    int node = blockIdx.x;
    int p0 = off[node], p1 = off[node + 1];
    int d = threadIdx.x;             // float4 lane: 256 x 4 = 1024 dims
    float4 acc = make_float4(0.f, 0.f, 0.f, 0.f);
    for (int p = p0; p < p1; p++) {
        int s = csr_src[p];
        float nrm = csr_nrm[p];
        float4 v = ((const float4*)&xw[(size_t)s * H2])[d];
        acc.x += v.x * nrm; acc.y += v.y * nrm;
        acc.z += v.z * nrm; acc.w += v.w * nrm;
    }
    float4 bb = ((const float4*)b)[d];
    float4 o;
    o.x = fmaxf(acc.x + bb.x, 0.f);
    o.y = fmaxf(acc.y + bb.y, 0.f);
    o.z = fmaxf(acc.z + bb.z, 0.f);
    o.w = fmaxf(acc.w + bb.w, 0.f);
    ((float4*)&x2[(size_t)node * H2])[d] = o;
}

// ---------------- pooling ----------------
__global__ void cnt_accum(const int* __restrict__ batch, float* cnt) {
    int i = blockIdx.x * 256 + threadIdx.x;
    if (i < N_NODES) atomicAdd(&cnt[batch[i]], 1.0f);
}

__global__ void pool_accum(const int* __restrict__ batch, const float* __restrict__ x2,
                           float* __restrict__ pooled) {
    int d  = blockIdx.x * 256 + threadIdx.x;   // 0..1023
    int i0 = blockIdx.y * 64;
    float acc = 0.0f;
    int gprev = -1;
    for (int i = 0; i < 64; i++) {
        int node = i0 + i;
        if (node >= N_NODES) break;
        int g = batch[node];
        if (g != gprev) {
            if (gprev >= 0) atomicAdd(&pooled[gprev * H2 + d], acc);
            acc = 0.0f; gprev = g;
        }
        acc += x2[(size_t)node * H2 + d];
    }
    if (gprev >= 0) atomicAdd(&pooled[gprev * H2 + d], acc);
}

__global__ void pool_norm(float* pooled, const float* cnt) {
    int idx = blockIdx.x * 256 + threadIdx.x;
    if (idx < N_GRAPHS * H2) {
        int g = idx >> 10;
        pooled[idx] /= fmaxf(cnt[g], 1.0f);
    }
}

// ---------------- MLP head ----------------
__global__ __launch_bounds__(256) void head_gemm(const float* __restrict__ In,
                                                 const float* __restrict__ W,
                                                 float* __restrict__ Out, int K, int N) {
    __shared__ __align__(16) float As[16][256];
    int n  = blockIdx.x * 256 + threadIdx.x;
    int m0 = blockIdx.y * 16;
    int k0 = blockIdx.z * 256;
    for (int t = threadIdx.x; t < 16 * 256; t += 256) {
        int r = t >> 8, k = t & 255;
        As[r][k] = In[(size_t)(m0 + r) * K + k0 + k];
    }
    __syncthreads();
    float acc[16] = {};
    for (int k = 0; k < 256; k += 4) {
        float w0 = W[(size_t)(k0 + k + 0) * N + n];
        float w1 = W[(size_t)(k0 + k + 1) * N + n];
        float w2 = W[(size_t)(k0 + k + 2) * N + n];
        float w3 = W[(size_t)(k0 + k + 3) * N + n];
#pragma unroll
        for (int r = 0; r < 16; r++) {
            float4 a = *(const float4*)&As[r][k];
            acc[r] += a.x * w0 + a.y * w1 + a.z * w2 + a.w * w3;
        }
    }
    for (int r = 0; r < 16; r++)
        atomicAdd(&Out[(size_t)(m0 + r) * N + n], acc[r]);
}

__global__ void bias_relu_MN(float* __restrict__ x, const float* __restrict__ b,
                             int N, int total) {
    int idx = blockIdx.x * 256 + threadIdx.x;
    if (idx < total) {
        int d = idx & (N - 1);    // N is a power of two
        x[idx] = fmaxf(x[idx] + b[d], 0.0f);
    }
}

__global__ void head3(const float* __restrict__ h2, const float* __restrict__ oW,
                      const float* __restrict__ ob, float* __restrict__ out) {
    int tid = threadIdx.x;          // 128 threads: m = tid/2, c = tid&1
    if (tid >= 128) return;
    int m = tid >> 1, c = tid & 1;
    float acc = 0.0f;
    for (int k = 0; k < 512; k++) acc += h2[m * 512 + k] * oW[k * 2 + c];
    out[tid] = acc + ob[c];
}

// ---------------- host ----------------
extern "C" void kernel_launch(void* const* d_in, const int* in_sizes, int n_in,
                              void* d_out, int out_size, void* d_ws, size_t ws_size,
                              hipStream_t stream) {
    const int*   ids   = (const int*)d_in[0];
    const float* other = (const float*)d_in[1];
    const int*   ei    = (const int*)d_in[2];
    const int*   batch = (const int*)d_in[3];
    const float* emb   = (const float*)d_in[4];
    const float* W1    = (const float*)d_in[5];
    const float* b1    = (const float*)d_in[6];
    const float* W2    = (const float*)d_in[7];
    const float* b2    = (const float*)d_in[8];
    const float* hW1   = (const float*)d_in[9];
    const float* hb1   = (const float*)d_in[10];
    const float* hW2   = (const float*)d_in[11];
    const float* hb2   = (const float*)d_in[12];
    const float* oW    = (const float*)d_in[13];
    const float* ob    = (const float*)d_in[14];
    float* out = (float*)d_out;

    char* ws = (char*)d_ws;
    size_t off_b = 0;
    auto alloc = [&](size_t bytes) {
        size_t p = (off_b + 255) & ~(size_t)255;
        off_b = p + bytes;
        return p;
    };
    size_t o_dinv = alloc((size_t)N_NODES * 4);
    size_t o_indeg= alloc((size_t)(N_NODES + 1) * 4);
    size_t o_off  = alloc((size_t)(N_NODES + 1) * 4);
    size_t o_cur  = alloc((size_t)N_NODES * 4);
    size_t o_csrc = alloc((size_t)N_TOT_E * 4);
    size_t o_cnrm = alloc((size_t)N_TOT_E * 4);
    size_t o_xf   = alloc((size_t)N_NODES * IN_GNN * 4);
    size_t o_agg1 = alloc((size_t)N_NODES * IN_GNN * 4);
    size_t o_x1   = alloc((size_t)N_NODES * H1 * 4);     // later reused as x2
    size_t o_xw2  = alloc((size_t)N_NODES * H2 * 4);
    size_t o_pool = alloc((size_t)N_GRAPHS * H2 * 4);
    size_t o_cnt  = alloc((size_t)N_GRAPHS * 4);
    size_t o_h1   = alloc((size_t)N_GRAPHS * 1024 * 4);
    size_t o_h2   = alloc((size_t)N_GRAPHS * 512 * 4);

    float* dinv = (float*)(ws + o_dinv);
    int*   indeg= (int*)(ws + o_indeg);
    int*   offs = (int*)(ws + o_off);
    int*   cur  = (int*)(ws + o_cur);
    int*   csrc = (int*)(ws + o_csrc);
    float* cnrm = (float*)(ws + o_cnrm);
    float* xf   = (float*)(ws + o_xf);
    float* agg1 = (float*)(ws + o_agg1);
    float* x1   = (float*)(ws + o_x1);
    float* xw2  = (float*)(ws + o_xw2);
    float* x2   = (float*)(ws + o_x1);    // alias: x1 dead after gemm2
    float* pooled = (float*)(ws + o_pool);
    float* cnt  = (float*)(ws + o_cnt);
    float* h1   = (float*)(ws + o_h1);
    float* h2   = (float*)(ws + o_h2);

    // degree (float, for dinv) + indegree (int, for CSR); self loop = init 1
    fill_f32<<<(N_NODES + 255) / 256, 256, 0, stream>>>(dinv, 1.0f, N_NODES);
    fill_i32<<<(N_NODES + 255) / 256, 256, 0, stream>>>(indeg, 1, N_NODES);
    deg_accum<<<(N_EDGES + 255) / 256, 256, 0, stream>>>(ei, dinv, indeg);
    deg_to_dinv<<<(N_NODES + 255) / 256, 256, 0, stream>>>(dinv);

    // CSR
    scan_offsets<<<1, 1024, 0, stream>>>(indeg, offs, cur);
    csr_fill<<<(N_TOT_E + 255) / 256, 256, 0, stream>>>(ei, dinv, cur, csrc, cnrm);

    // node features
    build_xfeat<<<(N_NODES * IN_GNN + 255) / 256, 256, 0, stream>>>(ids, other, emb, xf);

    // layer 1: aggregate(36) then GEMM
    agg_csr_36<<<(N_NODES * IN_GNN + 255) / 256, 256, 0, stream>>>(offs, csrc, cnrm, xf, agg1);
    gemm1_relu<<<dim3(H1 / 256, (N_NODES + 31) / 32), 256, 0, stream>>>(agg1, W1, b1, x1);

    // layer 2: GEMM then aggregate(1024) with bias+relu fused
    gemm2_f32<<<dim3(H2 / BN, (N_NODES + BM - 1) / BM), 256, 0, stream>>>(x1, W2, xw2);
    agg_csr_1024<<<N_NODES, 256, 0, stream>>>(offs, csrc, cnrm, xw2, b2, x2);

    // mean pool
    hipMemsetAsync(pooled, 0, (size_t)N_GRAPHS * H2 * 4, stream);
    hipMemsetAsync(cnt, 0, (size_t)N_GRAPHS * 4, stream);
    cnt_accum<<<(N_NODES + 255) / 256, 256, 0, stream>>>(batch, cnt);
    pool_accum<<<dim3(H2 / 256, (N_NODES + 63) / 64), 256, 0, stream>>>(batch, x2, pooled);
    pool_norm<<<(N_GRAPHS * H2 + 255) / 256, 256, 0, stream>>>(pooled, cnt);

    // head
    hipMemsetAsync(h1, 0, (size_t)N_GRAPHS * 1024 * 4, stream);
    head_gemm<<<dim3(1024 / 256, 4, 1024 / 256), 256, 0, stream>>>(pooled, hW1, h1, 1024, 1024);
    bias_relu_MN<<<(N_GRAPHS * 1024 + 255) / 256, 256, 0, stream>>>(h1, hb1, 1024, N_GRAPHS * 1024);

    hipMemsetAsync(h2, 0, (size_t)N_GRAPHS * 512 * 4, stream);
    head_gemm<<<dim3(512 / 256, 4, 1024 / 256), 256, 0, stream>>>(h1, hW2, h2, 1024, 512);
    bias_relu_MN<<<(N_GRAPHS * 512 + 255) / 256, 256, 0, stream>>>(h2, hb2, 512, N_GRAPHS * 512);

    head3<<<1, 128, 0, stream>>>(h2, oW, ob, out);
}

// Round 4
// 1105.334 us; speedup vs baseline: 5.6782x; 3.3025x over previous
//
#include <hip/hip_runtime.h>
#include <hip/hip_bf16.h>

#define N_NODES  20000
#define N_EDGES  160000
#define N_TOT_E  180000   // edges + self loops
#define N_GRAPHS 64
#define EMBED_DIM 32
#define IN_GNN   36
#define H1       2048
#define H2       1024
#define CHUNK0   10112    // 79 * 128; chunk1 = 9888 = N_NODES - CHUNK0

typedef unsigned short u16;
typedef short bf16x8 __attribute__((ext_vector_type(8)));
typedef float f32x4  __attribute__((ext_vector_type(4)));

__device__ inline u16 f32_to_bf16(float f) {
    union { float f; unsigned u; } v; v.f = f;
    unsigned lsb = (v.u >> 16) & 1u;
    return (u16)((v.u + 0x7fffu + lsb) >> 16);
}
__device__ inline float bf16_to_f32(u16 h) {
    union { unsigned u; float f; } v; v.u = ((unsigned)h) << 16;
    return v.f;
}

// ---------------- small utility kernels ----------------

__global__ void fill_f32(float* p, float v, int n) {
    int i = blockIdx.x * 256 + threadIdx.x;
    if (i < n) p[i] = v;
}

__global__ void fill_i32(int* p, int v, int n) {
    int i = blockIdx.x * 256 + threadIdx.x;
    if (i < n) p[i] = v;
}

__global__ void deg_accum(const int* __restrict__ ei, float* deg, int* indeg) {
    int e = blockIdx.x * 256 + threadIdx.x;
    if (e < N_EDGES) {
        int t = ei[N_EDGES + e];
        atomicAdd(&deg[t], 1.0f);
        atomicAdd(&indeg[t], 1);
    }
}

__global__ void deg_to_dinv(float* d) {
    int i = blockIdx.x * 256 + threadIdx.x;
    if (i < N_NODES) d[i] = rsqrtf(d[i]);   // deg >= 1 always (self loop)
}

__global__ void build_xfeat(const int* __restrict__ ids, const float* __restrict__ other,
                            const float* __restrict__ emb, float* __restrict__ xf) {
    int idx = blockIdx.x * 256 + threadIdx.x;   // node*36 + d
    if (idx >= N_NODES * IN_GNN) return;
    int i = idx / IN_GNN;
    int d = idx - i * IN_GNN;
    float v = (d < EMBED_DIM) ? emb[(size_t)ids[i] * EMBED_DIM + d]
                              : other[i * 4 + (d - EMBED_DIM)];
    xf[idx] = v;
}

// ---------------- CSR build ----------------
__global__ __launch_bounds__(1024) void scan_offsets(const int* __restrict__ indeg,
                                                     int* __restrict__ off,
                                                     int* __restrict__ cursor) {
    __shared__ int buf[1024];
    __shared__ int base_s;
    int tid = threadIdx.x;
    if (tid == 0) base_s = 0;
    __syncthreads();
    for (int start = 0; start < N_NODES; start += 1024) {
        int i = start + tid;
        int v = (i < N_NODES) ? indeg[i] : 0;
        buf[tid] = v;
        __syncthreads();
        for (int s = 1; s < 1024; s <<= 1) {
            int t = (tid >= s) ? buf[tid - s] : 0;
            __syncthreads();
            buf[tid] += t;
            __syncthreads();
        }
        int incl = buf[tid];
        int excl = incl - v;
        int base = base_s;
        if (i < N_NODES) {
            int o = base + excl;
            off[i] = o;
            cursor[i] = o;
        }
        __syncthreads();
        if (tid == 1023) base_s = base + incl;
        __syncthreads();
    }
    if (tid == 0) off[N_NODES] = N_TOT_E;
}

__global__ void csr_fill(const int* __restrict__ ei, const float* __restrict__ dinv,
                         int* __restrict__ cursor,
                         int* __restrict__ csr_src, float* __restrict__ csr_nrm) {
    int e = blockIdx.x * 256 + threadIdx.x;
    if (e >= N_TOT_E) return;
    int s, t;
    if (e < N_EDGES) { s = ei[e]; t = ei[N_EDGES + e]; }
    else             { s = t = e - N_EDGES; }
    int pos = atomicAdd(&cursor[t], 1);
    csr_src[pos] = s;
    csr_nrm[pos] = dinv[s] * dinv[t];
}

// ---------------- layer-1 aggregation via CSR gather (36-dim) ----------------
__global__ void agg_csr_36(const int* __restrict__ off, const int* __restrict__ csr_src,
                           const float* __restrict__ csr_nrm,
                           const float* __restrict__ xf, float* __restrict__ agg) {
    int idx = blockIdx.x * 256 + threadIdx.x;   // node*36 + d
    if (idx >= N_NODES * IN_GNN) return;
    int node = idx / IN_GNN;
    int d = idx - node * IN_GNN;
    int p0 = off[node], p1 = off[node + 1];
    float acc = 0.0f;
    for (int p = p0; p < p1; p++)
        acc += xf[csr_src[p] * IN_GNN + d] * csr_nrm[p];
    agg[idx] = acc;
}

// ---------------- GEMM1: agg1[rows,36] @ W1[36,2048] + b1, relu -> chunk-local hi/lo bf16
__global__ __launch_bounds__(256) void gemm1_relu(const float* __restrict__ A,
                                                  const float* __restrict__ W,
                                                  const float* __restrict__ b,
                                                  u16* __restrict__ Xh,
                                                  u16* __restrict__ Xl,
                                                  int rowbase, int nrows) {
    __shared__ __align__(16) float As[32][IN_GNN];   // 32x36 f32
    int rb = blockIdx.y * 32;                        // chunk-local
    int n  = blockIdx.x * 256 + threadIdx.x;
    for (int t = threadIdx.x; t < 32 * IN_GNN; t += 256) {
        int r = t / IN_GNN, k = t - r * IN_GNN;
        int lr = rb + r;
        As[r][k] = (lr < nrows) ? A[(size_t)(rowbase + lr) * IN_GNN + k] : 0.0f;
    }
    __syncthreads();
    float acc[32];
#pragma unroll
    for (int r = 0; r < 32; r++) acc[r] = 0.0f;
#pragma unroll
    for (int k = 0; k < IN_GNN; k += 4) {
        float w0 = W[(size_t)(k + 0) * H1 + n];
        float w1 = W[(size_t)(k + 1) * H1 + n];
        float w2 = W[(size_t)(k + 2) * H1 + n];
        float w3 = W[(size_t)(k + 3) * H1 + n];
#pragma unroll
        for (int r = 0; r < 32; r++) {
            float4 a = *(const float4*)&As[r][k];
            acc[r] += a.x * w0 + a.y * w1 + a.z * w2 + a.w * w3;
        }
    }
    float bias = b[n];
    for (int r = 0; r < 32; r++) {
        int lr = rb + r;
        if (lr < nrows) {
            float v = fmaxf(acc[r] + bias, 0.0f);
            u16 hi = f32_to_bf16(v);
            Xh[(size_t)lr * H1 + n] = hi;
            Xl[(size_t)lr * H1 + n] = f32_to_bf16(v - bf16_to_f32(hi));
        }
    }
}

// ---------------- W2 [2048,1024] f32 -> transposed hi/lo bf16 [1024,2048] ----------
__global__ __launch_bounds__(256) void conv_w2(const float* __restrict__ W,
                                               u16* __restrict__ Bh,
                                               u16* __restrict__ Bl) {
    __shared__ float t[32][33];
    int bk = blockIdx.x * 32;   // k block
    int bn = blockIdx.y * 32;   // n block
    int tx = threadIdx.x & 31, ty = threadIdx.x >> 5;   // 32 x 8
#pragma unroll
    for (int i = 0; i < 32; i += 8)
        t[ty + i][tx] = W[(size_t)(bk + ty + i) * H2 + bn + tx];
    __syncthreads();
#pragma unroll
    for (int i = 0; i < 32; i += 8) {
        float v = t[tx][ty + i];            // = W[bk+tx][bn+ty+i]
        u16 hi = f32_to_bf16(v);
        u16 lo = f32_to_bf16(v - bf16_to_f32(hi));
        size_t o = (size_t)(bn + ty + i) * H1 + bk + tx;   // Bt[n][k]
        Bh[o] = hi;
        Bl[o] = lo;
    }
}

// ---------------- GEMM2 via bf16 MFMA (hi/lo split, 3 products) -----------------
// C[rowbase+lr, 1024] = (Ah+Al)[lr,2048] @ (Bh+Bl)^T-stored[1024,2048]
// 128x128 tile, BK=32, 4 waves; each wave computes 64x64 = 4x4 frags of 16x16x32.
__global__ __launch_bounds__(256) void gemm2_mfma(const u16* __restrict__ Ah,
                                                  const u16* __restrict__ Al,
                                                  const u16* __restrict__ Bh,
                                                  const u16* __restrict__ Bl,
                                                  float* __restrict__ C,
                                                  int rowbase, int nrows) {
    __shared__ u16 lds[4][128 * 32];   // Ah, Al, Bh, Bl tiles: 8 KB each
    const int tid  = threadIdx.x;
    const int wid  = tid >> 6;
    const int lane = tid & 63;
    const int wr   = wid >> 1, wc = wid & 1;
    const int row0 = blockIdx.y * 128;          // chunk-local
    const int col0 = blockIdx.x * 128;

    // staging: wave wid stages tile wid (8 x global_load_lds dwordx4)
    const u16* gbase;
    int rbase;
    if      (wid == 0) { gbase = Ah; rbase = row0; }
    else if (wid == 1) { gbase = Al; rbase = row0; }
    else if (wid == 2) { gbase = Bh; rbase = col0; }
    else               { gbase = Bl; rbase = col0; }
    u16* myl = lds[wid];
    const int r_l  = lane >> 2;        // 0..15
    const int ks_l = (lane & 3) * 8;   // 0,8,16,24  (lds dest byte = lane*16, linear)

    int rows[8];
#pragma unroll
    for (int i = 0; i < 8; i++) {
        int r = rbase + i * 16 + r_l;
        if (wid < 2 && r > nrows - 1) r = nrows - 1;   // clamp A-side reads to chunk
        rows[i] = r;
    }

    f32x4 acc[4][4] = {};

    for (int kt = 0; kt < H1 / 32; ++kt) {
        int k0 = kt * 32;
        __syncthreads();   // previous compute done before overwrite
#pragma unroll
        for (int i = 0; i < 8; i++) {
            const u16* g = gbase + (size_t)rows[i] * H1 + k0 + ks_l;
            __builtin_amdgcn_global_load_lds(
                (const __attribute__((address_space(1))) void*)g,
                (__attribute__((address_space(3))) void*)(myl + i * 512),
                16, 0, 0);
        }
        __syncthreads();   // compiler drains vmcnt before barrier

        bf16x8 afh[4], afl[4];
#pragma unroll
        for (int mi = 0; mi < 4; mi++) {
            int r   = wr * 64 + mi * 16 + (lane & 15);
            int off = r * 32 + (lane >> 4) * 8;
            afh[mi] = *(const bf16x8*)&lds[0][off];
            afl[mi] = *(const bf16x8*)&lds[1][off];
        }
#pragma unroll
        for (int ni = 0; ni < 4; ni++) {
            int c   = wc * 64 + ni * 16 + (lane & 15);
            int off = c * 32 + (lane >> 4) * 8;
            bf16x8 bfh = *(const bf16x8*)&lds[2][off];
            bf16x8 bfl = *(const bf16x8*)&lds[3][off];
#pragma unroll
            for (int mi = 0; mi < 4; mi++) {
                acc[mi][ni] = __builtin_amdgcn_mfma_f32_16x16x32_bf16(afh[mi], bfh, acc[mi][ni], 0, 0, 0);
                acc[mi][ni] = __builtin_amdgcn_mfma_f32_16x16x32_bf16(afh[mi], bfl, acc[mi][ni], 0, 0, 0);
                acc[mi][ni] = __builtin_amdgcn_mfma_f32_16x16x32_bf16(afl[mi], bfh, acc[mi][ni], 0, 0, 0);
            }
        }
    }

    // C/D layout: col = lane&15, row = (lane>>4)*4 + j  [m89/m91 verified]
#pragma unroll
    for (int mi = 0; mi < 4; mi++) {
#pragma unroll
        for (int ni = 0; ni < 4; ni++) {
            int col = col0 + wc * 64 + ni * 16 + (lane & 15);
#pragma unroll
            for (int j = 0; j < 4; j++) {
                int lr = row0 + wr * 64 + mi * 16 + (lane >> 4) * 4 + j;
                if (lr < nrows) C[(size_t)(rowbase + lr) * H2 + col] = acc[mi][ni][j];
            }
        }
    }
}

// ---------------- layer-2 aggregation via CSR gather (1024-dim), bias+relu fused ----
__global__ __launch_bounds__(256) void agg_csr_1024(const int* __restrict__ off,
                                                    const int* __restrict__ csr_src,
                                                    const float* __restrict__ csr_nrm,
                                                    const float* __restrict__ xw,
                                                    const float* __restrict__ b,
                                                    float* __restrict__ x2) {
    int node = blockIdx.x;
    int p0 = off[node], p1 = off[node + 1];
    int d = threadIdx.x;             // float4 lane: 256 x 4 = 1024 dims
    float4 acc = make_float4(0.f, 0.f, 0.f, 0.f);
    for (int p = p0; p < p1; p++) {
        int s = csr_src[p];
        float nrm = csr_nrm[p];
        float4 v = ((const float4*)&xw[(size_t)s * H2])[d];
        acc.x += v.x * nrm; acc.y += v.y * nrm;
        acc.z += v.z * nrm; acc.w += v.w * nrm;
    }
    float4 bb = ((const float4*)b)[d];
    float4 o;
    o.x = fmaxf(acc.x + bb.x, 0.f);
    o.y = fmaxf(acc.y + bb.y, 0.f);
    o.z = fmaxf(acc.z + bb.z, 0.f);
    o.w = fmaxf(acc.w + bb.w, 0.f);
    ((float4*)&x2[(size_t)node * H2])[d] = o;
}

// ---------------- pooling ----------------
__global__ void cnt_accum(const int* __restrict__ batch, float* cnt) {
    int i = blockIdx.x * 256 + threadIdx.x;
    if (i < N_NODES) atomicAdd(&cnt[batch[i]], 1.0f);
}

__global__ void pool_accum(const int* __restrict__ batch, const float* __restrict__ x2,
                           float* __restrict__ pooled) {
    int d  = blockIdx.x * 256 + threadIdx.x;   // 0..1023
    int i0 = blockIdx.y * 64;
    float acc = 0.0f;
    int gprev = -1;
    for (int i = 0; i < 64; i++) {
        int node = i0 + i;
        if (node >= N_NODES) break;
        int g = batch[node];
        if (g != gprev) {
            if (gprev >= 0) atomicAdd(&pooled[gprev * H2 + d], acc);
            acc = 0.0f; gprev = g;
        }
        acc += x2[(size_t)node * H2 + d];
    }
    if (gprev >= 0) atomicAdd(&pooled[gprev * H2 + d], acc);
}

__global__ void pool_norm(float* pooled, const float* cnt) {
    int idx = blockIdx.x * 256 + threadIdx.x;
    if (idx < N_GRAPHS * H2) {
        int g = idx >> 10;
        pooled[idx] /= fmaxf(cnt[g], 1.0f);
    }
}

// ---------------- MLP head ----------------
__global__ __launch_bounds__(256) void head_gemm(const float* __restrict__ In,
                                                 const float* __restrict__ W,
                                                 float* __restrict__ Out, int K, int N) {
    __shared__ __align__(16) float As[16][256];
    int n  = blockIdx.x * 256 + threadIdx.x;
    int m0 = blockIdx.y * 16;
    int k0 = blockIdx.z * 256;
    for (int t = threadIdx.x; t < 16 * 256; t += 256) {
        int r = t >> 8, k = t & 255;
        As[r][k] = In[(size_t)(m0 + r) * K + k0 + k];
    }
    __syncthreads();
    float acc[16] = {};
    for (int k = 0; k < 256; k += 4) {
        float w0 = W[(size_t)(k0 + k + 0) * N + n];
        float w1 = W[(size_t)(k0 + k + 1) * N + n];
        float w2 = W[(size_t)(k0 + k + 2) * N + n];
        float w3 = W[(size_t)(k0 + k + 3) * N + n];
#pragma unroll
        for (int r = 0; r < 16; r++) {
            float4 a = *(const float4*)&As[r][k];
            acc[r] += a.x * w0 + a.y * w1 + a.z * w2 + a.w * w3;
        }
    }
    for (int r = 0; r < 16; r++)
        atomicAdd(&Out[(size_t)(m0 + r) * N + n], acc[r]);
}

__global__ void bias_relu_MN(float* __restrict__ x, const float* __restrict__ b,
                             int N, int total) {
    int idx = blockIdx.x * 256 + threadIdx.x;
    if (idx < total) {
        int d = idx & (N - 1);    // N is a power of two
        x[idx] = fmaxf(x[idx] + b[d], 0.0f);
    }
}

__global__ void head3(const float* __restrict__ h2, const float* __restrict__ oW,
                      const float* __restrict__ ob, float* __restrict__ out) {
    int tid = threadIdx.x;          // 128 threads: m = tid/2, c = tid&1
    if (tid >= 128) return;
    int m = tid >> 1, c = tid & 1;
    float acc = 0.0f;
    for (int k = 0; k < 512; k++) acc += h2[m * 512 + k] * oW[k * 2 + c];
    out[tid] = acc + ob[c];
}

// ---------------- host ----------------
extern "C" void kernel_launch(void* const* d_in, const int* in_sizes, int n_in,
                              void* d_out, int out_size, void* d_ws, size_t ws_size,
                              hipStream_t stream) {
    const int*   ids   = (const int*)d_in[0];
    const float* other = (const float*)d_in[1];
    const int*   ei    = (const int*)d_in[2];
    const int*   batch = (const int*)d_in[3];
    const float* emb   = (const float*)d_in[4];
    const float* W1    = (const float*)d_in[5];
    const float* b1    = (const float*)d_in[6];
    const float* W2    = (const float*)d_in[7];
    const float* b2    = (const float*)d_in[8];
    const float* hW1   = (const float*)d_in[9];
    const float* hb1   = (const float*)d_in[10];
    const float* hW2   = (const float*)d_in[11];
    const float* hb2   = (const float*)d_in[12];
    const float* oW    = (const float*)d_in[13];
    const float* ob    = (const float*)d_in[14];
    float* out = (float*)d_out;

    char* ws = (char*)d_ws;
    size_t off_b = 0;
    auto alloc = [&](size_t bytes) {
        size_t p = (off_b + 255) & ~(size_t)255;
        off_b = p + bytes;
        return p;
    };
    // total ~181 MB (chunked x1 keeps us well under the R2-proven 254 MB)
    size_t o_dinv = alloc((size_t)N_NODES * 4);
    size_t o_indeg= alloc((size_t)(N_NODES + 1) * 4);
    size_t o_off  = alloc((size_t)(N_NODES + 1) * 4);
    size_t o_cur  = alloc((size_t)N_NODES * 4);
    size_t o_csrc = alloc((size_t)N_TOT_E * 4);
    size_t o_cnrm = alloc((size_t)N_TOT_E * 4);
    size_t o_xf   = alloc((size_t)N_NODES * IN_GNN * 4);
    size_t o_agg1 = alloc((size_t)N_NODES * IN_GNN * 4);
    size_t o_x1h  = alloc((size_t)CHUNK0 * H1 * 2);      // chunk-local bf16 hi
    size_t o_x1l  = alloc((size_t)CHUNK0 * H1 * 2);      // chunk-local bf16 lo
    size_t o_w2h  = alloc((size_t)H2 * H1 * 2);          // W2^T hi bf16 [1024][2048]
    size_t o_w2l  = alloc((size_t)H2 * H1 * 2);
    size_t o_xw2  = alloc((size_t)N_NODES * H2 * 4);
    size_t o_pool = alloc((size_t)N_GRAPHS * H2 * 4);
    size_t o_cnt  = alloc((size_t)N_GRAPHS * 4);
    size_t o_h1   = alloc((size_t)N_GRAPHS * 1024 * 4);
    size_t o_h2   = alloc((size_t)N_GRAPHS * 512 * 4);

    float* dinv = (float*)(ws + o_dinv);
    int*   indeg= (int*)(ws + o_indeg);
    int*   offs = (int*)(ws + o_off);
    int*   cur  = (int*)(ws + o_cur);
    int*   csrc = (int*)(ws + o_csrc);
    float* cnrm = (float*)(ws + o_cnrm);
    float* xf   = (float*)(ws + o_xf);
    float* agg1 = (float*)(ws + o_agg1);
    u16*   x1h  = (u16*)(ws + o_x1h);
    u16*   x1l  = (u16*)(ws + o_x1l);
    u16*   w2h  = (u16*)(ws + o_w2h);
    u16*   w2l  = (u16*)(ws + o_w2l);
    float* xw2  = (float*)(ws + o_xw2);
    // x2 aliases the x1h+x1l region (82.8 MB contiguous >= 80 MB needed; both dead then)
    float* x2   = (float*)(ws + o_x1h);
    float* pooled = (float*)(ws + o_pool);
    float* cnt  = (float*)(ws + o_cnt);
    float* h1   = (float*)(ws + o_h1);
    float* h2   = (float*)(ws + o_h2);

    // degree (float, for dinv) + indegree (int, for CSR); self loop = init 1
    fill_f32<<<(N_NODES + 255) / 256, 256, 0, stream>>>(dinv, 1.0f, N_NODES);
    fill_i32<<<(N_NODES + 255) / 256, 256, 0, stream>>>(indeg, 1, N_NODES);
    deg_accum<<<(N_EDGES + 255) / 256, 256, 0, stream>>>(ei, dinv, indeg);
    deg_to_dinv<<<(N_NODES + 255) / 256, 256, 0, stream>>>(dinv);

    // CSR
    scan_offsets<<<1, 1024, 0, stream>>>(indeg, offs, cur);
    csr_fill<<<(N_TOT_E + 255) / 256, 256, 0, stream>>>(ei, dinv, cur, csrc, cnrm);

    // node features + layer-1 aggregation (full graph)
    build_xfeat<<<(N_NODES * IN_GNN + 255) / 256, 256, 0, stream>>>(ids, other, emb, xf);
    agg_csr_36<<<(N_NODES * IN_GNN + 255) / 256, 256, 0, stream>>>(offs, csrc, cnrm, xf, agg1);

    // W2 -> transposed hi/lo bf16 (once)
    conv_w2<<<dim3(H1 / 32, H2 / 32), 256, 0, stream>>>(W2, w2h, w2l);

    // layers 1+2 GEMMs in two M-chunks to bound workspace
    {
        const int c0 = CHUNK0, c1 = N_NODES - CHUNK0;   // 10112, 9888
        // chunk 0
        gemm1_relu<<<dim3(H1 / 256, c0 / 32), 256, 0, stream>>>(agg1, W1, b1, x1h, x1l, 0, c0);
        gemm2_mfma<<<dim3(H2 / 128, c0 / 128), 256, 0, stream>>>(x1h, x1l, w2h, w2l, xw2, 0, c0);
        // chunk 1 (stream order guarantees chunk-0 gemm2 finished reading x1h/x1l)
        gemm1_relu<<<dim3(H1 / 256, c1 / 32), 256, 0, stream>>>(agg1, W1, b1, x1h, x1l, c0, c1);
        gemm2_mfma<<<dim3(H2 / 128, (c1 + 127) / 128), 256, 0, stream>>>(x1h, x1l, w2h, w2l, xw2, c0, c1);
    }

    // layer-2 aggregation with bias+relu fused (x2 overwrites dead x1h/x1l region)
    agg_csr_1024<<<N_NODES, 256, 0, stream>>>(offs, csrc, cnrm, xw2, b2, x2);

    // mean pool
    hipMemsetAsync(pooled, 0, (size_t)N_GRAPHS * H2 * 4, stream);
    hipMemsetAsync(cnt, 0, (size_t)N_GRAPHS * 4, stream);
    cnt_accum<<<(N_NODES + 255) / 256, 256, 0, stream>>>(batch, cnt);
    pool_accum<<<dim3(H2 / 256, (N_NODES + 63) / 64), 256, 0, stream>>>(batch, x2, pooled);
    pool_norm<<<(N_GRAPHS * H2 + 255) / 256, 256, 0, stream>>>(pooled, cnt);

    // head
    hipMemsetAsync(h1, 0, (size_t)N_GRAPHS * 1024 * 4, stream);
    head_gemm<<<dim3(1024 / 256, 4, 1024 / 256), 256, 0, stream>>>(pooled, hW1, h1, 1024, 1024);
    bias_relu_MN<<<(N_GRAPHS * 1024 + 255) / 256, 256, 0, stream>>>(h1, hb1, 1024, N_GRAPHS * 1024);

    hipMemsetAsync(h2, 0, (size_t)N_GRAPHS * 512 * 4, stream);
    head_gemm<<<dim3(512 / 256, 4, 1024 / 256), 256, 0, stream>>>(h1, hW2, h2, 1024, 512);
    bias_relu_MN<<<(N_GRAPHS * 512 + 255) / 256, 256, 0, stream>>>(h2, hb2, 512, N_GRAPHS * 512);

    head3<<<1, 128, 0, stream>>>(h2, oW, ob, out);
}

// Round 5
// 1067.978 us; speedup vs baseline: 5.8768x; 1.0350x over previous
//
#include <hip/hip_runtime.h>
#include <hip/hip_bf16.h>

#define N_NODES  20000
#define N_EDGES  160000
#define N_TOT_E  180000   // edges + self loops
#define N_GRAPHS 64
#define EMBED_DIM 32
#define IN_GNN   36
#define H1       2048
#define H2       1024
#define CHUNK0   10112    // 79 * 128; chunk1 = 9888 = N_NODES - CHUNK0

typedef unsigned short u16;
typedef short bf16x8 __attribute__((ext_vector_type(8)));
typedef float f32x4  __attribute__((ext_vector_type(4)));

__device__ inline u16 f32_to_bf16(float f) {
    union { float f; unsigned u; } v; v.f = f;
    unsigned lsb = (v.u >> 16) & 1u;
    return (u16)((v.u + 0x7fffu + lsb) >> 16);
}
__device__ inline float bf16_to_f32(u16 h) {
    union { unsigned u; float f; } v; v.u = ((unsigned)h) << 16;
    return v.f;
}

// ---------------- small utility kernels ----------------

__global__ void fill_i32(int* p, int v, int n) {
    int i = blockIdx.x * 256 + threadIdx.x;
    if (i < n) p[i] = v;
}

__global__ void deg_accum(const int* __restrict__ ei, int* indeg) {
    int e = blockIdx.x * 256 + threadIdx.x;
    if (e < N_EDGES) atomicAdd(&indeg[ei[N_EDGES + e]], 1);
}

__global__ void deg_to_dinv(const int* __restrict__ indeg, float* __restrict__ d) {
    int i = blockIdx.x * 256 + threadIdx.x;
    if (i < N_NODES) d[i] = rsqrtf((float)indeg[i]);   // deg >= 1 (self loop)
}

__global__ void build_xfeat(const int* __restrict__ ids, const float* __restrict__ other,
                            const float* __restrict__ emb, float* __restrict__ xf) {
    int idx = blockIdx.x * 256 + threadIdx.x;   // node*36 + d
    if (idx >= N_NODES * IN_GNN) return;
    int i = idx / IN_GNN;
    int d = idx - i * IN_GNN;
    float v = (d < EMBED_DIM) ? emb[(size_t)ids[i] * EMBED_DIM + d]
                              : other[i * 4 + (d - EMBED_DIM)];
    xf[idx] = v;
}

// ---------------- CSR build ----------------
__global__ __launch_bounds__(1024) void scan_offsets(const int* __restrict__ indeg,
                                                     int* __restrict__ off,
                                                     int* __restrict__ cursor) {
    __shared__ int buf[1024];
    __shared__ int base_s;
    int tid = threadIdx.x;
    if (tid == 0) base_s = 0;
    __syncthreads();
    for (int start = 0; start < N_NODES; start += 1024) {
        int i = start + tid;
        int v = (i < N_NODES) ? indeg[i] : 0;
        buf[tid] = v;
        __syncthreads();
        for (int s = 1; s < 1024; s <<= 1) {
            int t = (tid >= s) ? buf[tid - s] : 0;
            __syncthreads();
            buf[tid] += t;
            __syncthreads();
        }
        int incl = buf[tid];
        int excl = incl - v;
        int base = base_s;
        if (i < N_NODES) {
            int o = base + excl;
            off[i] = o;
            cursor[i] = o;
        }
        __syncthreads();
        if (tid == 1023) base_s = base + incl;
        __syncthreads();
    }
    if (tid == 0) off[N_NODES] = N_TOT_E;
}

__global__ void csr_fill(const int* __restrict__ ei, const float* __restrict__ dinv,
                         int* __restrict__ cursor,
                         int* __restrict__ csr_src, float* __restrict__ csr_nrm) {
    int e = blockIdx.x * 256 + threadIdx.x;
    if (e >= N_TOT_E) return;
    int s, t;
    if (e < N_EDGES) { s = ei[e]; t = ei[N_EDGES + e]; }
    else             { s = t = e - N_EDGES; }
    int pos = atomicAdd(&cursor[t], 1);
    csr_src[pos] = s;
    csr_nrm[pos] = dinv[s] * dinv[t];
}

// ---------------- layer-1 aggregation via CSR gather (36-dim) ----------------
__global__ void agg_csr_36(const int* __restrict__ off, const int* __restrict__ csr_src,
                           const float* __restrict__ csr_nrm,
                           const float* __restrict__ xf, float* __restrict__ agg) {
    int idx = blockIdx.x * 256 + threadIdx.x;   // node*36 + d
    if (idx >= N_NODES * IN_GNN) return;
    int node = idx / IN_GNN;
    int d = idx - node * IN_GNN;
    int p0 = off[node], p1 = off[node + 1];
    float acc = 0.0f;
    for (int p = p0; p < p1; p++)
        acc += xf[csr_src[p] * IN_GNN + d] * csr_nrm[p];
    agg[idx] = acc;
}

// ---------------- GEMM1: agg1[rows,36] @ W1[36,2048] + b1, relu -> chunk-local hi/lo bf16
__global__ __launch_bounds__(256) void gemm1_relu(const float* __restrict__ A,
                                                  const float* __restrict__ W,
                                                  const float* __restrict__ b,
                                                  u16* __restrict__ Xh,
                                                  u16* __restrict__ Xl,
                                                  int rowbase, int nrows) {
    __shared__ __align__(16) float As[32][IN_GNN];   // 32x36 f32
    int rb = blockIdx.y * 32;                        // chunk-local
    int n  = blockIdx.x * 256 + threadIdx.x;
    for (int t = threadIdx.x; t < 32 * IN_GNN; t += 256) {
        int r = t / IN_GNN, k = t - r * IN_GNN;
        int lr = rb + r;
        As[r][k] = (lr < nrows) ? A[(size_t)(rowbase + lr) * IN_GNN + k] : 0.0f;
    }
    __syncthreads();
    float acc[32];
#pragma unroll
    for (int r = 0; r < 32; r++) acc[r] = 0.0f;
#pragma unroll
    for (int k = 0; k < IN_GNN; k += 4) {
        float w0 = W[(size_t)(k + 0) * H1 + n];
        float w1 = W[(size_t)(k + 1) * H1 + n];
        float w2 = W[(size_t)(k + 2) * H1 + n];
        float w3 = W[(size_t)(k + 3) * H1 + n];
#pragma unroll
        for (int r = 0; r < 32; r++) {
            float4 a = *(const float4*)&As[r][k];
            acc[r] += a.x * w0 + a.y * w1 + a.z * w2 + a.w * w3;
        }
    }
    float bias = b[n];
    for (int r = 0; r < 32; r++) {
        int lr = rb + r;
        if (lr < nrows) {
            float v = fmaxf(acc[r] + bias, 0.0f);
            u16 hi = f32_to_bf16(v);
            Xh[(size_t)lr * H1 + n] = hi;
            Xl[(size_t)lr * H1 + n] = f32_to_bf16(v - bf16_to_f32(hi));
        }
    }
}

// ---------------- W2 [2048,1024] f32 -> transposed hi/lo bf16 [1024,2048] ----------
__global__ __launch_bounds__(256) void conv_w2(const float* __restrict__ W,
                                               u16* __restrict__ Bh,
                                               u16* __restrict__ Bl) {
    __shared__ float t[32][33];
    int bk = blockIdx.x * 32;   // k block
    int bn = blockIdx.y * 32;   // n block
    int tx = threadIdx.x & 31, ty = threadIdx.x >> 5;   // 32 x 8
#pragma unroll
    for (int i = 0; i < 32; i += 8)
        t[ty + i][tx] = W[(size_t)(bk + ty + i) * H2 + bn + tx];
    __syncthreads();
#pragma unroll
    for (int i = 0; i < 32; i += 8) {
        float v = t[tx][ty + i];            // = W[bk+tx][bn+ty+i]
        u16 hi = f32_to_bf16(v);
        u16 lo = f32_to_bf16(v - bf16_to_f32(hi));
        size_t o = (size_t)(bn + ty + i) * H1 + bk + tx;   // Bt[n][k]
        Bh[o] = hi;
        Bl[o] = lo;
    }
}

// ---------------- GEMM2 via bf16 MFMA (hi/lo split, 3 products) -----------------
// C[rowbase+lr, 1024] = (Ah+Al)[lr,2048] @ (Bh+Bl)^T-stored[1024,2048]
// 128x128 tile, BK=32, 4 waves; each wave computes 64x64 = 4x4 frags of 16x16x32.
// XCD-aware remap: blocks sharing one A row-panel land on ONE XCD (its L2 keeps
// the panel), cutting A re-fetch from HBM ~8x. Valid: NB % 8 == 0 for both chunks.
__global__ __launch_bounds__(256) void gemm2_mfma(const u16* __restrict__ Ah,
                                                  const u16* __restrict__ Al,
                                                  const u16* __restrict__ Bh,
                                                  const u16* __restrict__ Bl,
                                                  float* __restrict__ C,
                                                  int rowbase, int nrows) {
    __shared__ u16 lds[4][128 * 32];   // Ah, Al, Bh, Bl tiles: 8 KB each
    const int tid  = threadIdx.x;
    const int wid  = tid >> 6;
    const int lane = tid & 63;
    const int wr   = wid >> 1, wc = wid & 1;

    // ---- XCD-aware bijective remap (gridDim.x == 8) ----
    int NB = (int)(gridDim.x * gridDim.y);
    int b  = (int)(blockIdx.y * gridDim.x + blockIdx.x);
    int lin = b;
    if ((NB & 7) == 0) {
        int xcd = b & 7, j = b >> 3;      // round-robin slot -> contiguous run
        lin = xcd * (NB >> 3) + j;
    }
    const int col0 = (lin & 7) * 128;
    const int row0 = (lin >> 3) * 128;    // chunk-local

    // staging: wave wid stages tile wid (8 x global_load_lds dwordx4)
    const u16* gbase;
    int rbase;
    if      (wid == 0) { gbase = Ah; rbase = row0; }
    else if (wid == 1) { gbase = Al; rbase = row0; }
    else if (wid == 2) { gbase = Bh; rbase = col0; }
    else               { gbase = Bl; rbase = col0; }
    u16* myl = lds[wid];
    const int r_l  = lane >> 2;        // 0..15
    const int ks_l = (lane & 3) * 8;   // 0,8,16,24  (lds dest byte = lane*16, linear)

    int rows[8];
#pragma unroll
    for (int i = 0; i < 8; i++) {
        int r = rbase + i * 16 + r_l;
        if (wid < 2 && r > nrows - 1) r = nrows - 1;   // clamp A-side reads to chunk
        rows[i] = r;
    }

    f32x4 acc[4][4] = {};

    for (int kt = 0; kt < H1 / 32; ++kt) {
        int k0 = kt * 32;
        __syncthreads();   // previous compute done before overwrite
#pragma unroll
        for (int i = 0; i < 8; i++) {
            const u16* g = gbase + (size_t)rows[i] * H1 + k0 + ks_l;
            __builtin_amdgcn_global_load_lds(
                (const __attribute__((address_space(1))) void*)g,
                (__attribute__((address_space(3))) void*)(myl + i * 512),
                16, 0, 0);
        }
        __syncthreads();   // compiler drains vmcnt before barrier

        bf16x8 afh[4], afl[4];
#pragma unroll
        for (int mi = 0; mi < 4; mi++) {
            int r   = wr * 64 + mi * 16 + (lane & 15);
            int off = r * 32 + (lane >> 4) * 8;
            afh[mi] = *(const bf16x8*)&lds[0][off];
            afl[mi] = *(const bf16x8*)&lds[1][off];
        }
#pragma unroll
        for (int ni = 0; ni < 4; ni++) {
            int c   = wc * 64 + ni * 16 + (lane & 15);
            int off = c * 32 + (lane >> 4) * 8;
            bf16x8 bfh = *(const bf16x8*)&lds[2][off];
            bf16x8 bfl = *(const bf16x8*)&lds[3][off];
#pragma unroll
            for (int mi = 0; mi < 4; mi++) {
                acc[mi][ni] = __builtin_amdgcn_mfma_f32_16x16x32_bf16(afh[mi], bfh, acc[mi][ni], 0, 0, 0);
                acc[mi][ni] = __builtin_amdgcn_mfma_f32_16x16x32_bf16(afh[mi], bfl, acc[mi][ni], 0, 0, 0);
                acc[mi][ni] = __builtin_amdgcn_mfma_f32_16x16x32_bf16(afl[mi], bfh, acc[mi][ni], 0, 0, 0);
            }
        }
    }

    // C/D layout: col = lane&15, row = (lane>>4)*4 + j  [m89/m91 verified]
#pragma unroll
    for (int mi = 0; mi < 4; mi++) {
#pragma unroll
        for (int ni = 0; ni < 4; ni++) {
            int col = col0 + wc * 64 + ni * 16 + (lane & 15);
#pragma unroll
            for (int j = 0; j < 4; j++) {
                int lr = row0 + wr * 64 + mi * 16 + (lane >> 4) * 4 + j;
                if (lr < nrows) C[(size_t)(rowbase + lr) * H2 + col] = acc[mi][ni][j];
            }
        }
    }
}

// ---------------- layer-2 aggregation via CSR gather (1024-dim), bias+relu fused ----
__global__ __launch_bounds__(256) void agg_csr_1024(const int* __restrict__ off,
                                                    const int* __restrict__ csr_src,
                                                    const float* __restrict__ csr_nrm,
                                                    const float* __restrict__ xw,
                                                    const float* __restrict__ b,
                                                    float* __restrict__ x2) {
    int node = blockIdx.x;
    int p0 = off[node], p1 = off[node + 1];
    int d = threadIdx.x;             // float4 lane: 256 x 4 = 1024 dims
    float4 a0 = make_float4(0.f, 0.f, 0.f, 0.f);
    float4 a1 = make_float4(0.f, 0.f, 0.f, 0.f);
    int p = p0;
    for (; p + 1 < p1; p += 2) {
        int   s0 = csr_src[p],     s1 = csr_src[p + 1];
        float n0 = csr_nrm[p],     n1 = csr_nrm[p + 1];
        float4 v0 = ((const float4*)&xw[(size_t)s0 * H2])[d];
        float4 v1 = ((const float4*)&xw[(size_t)s1 * H2])[d];
        a0.x += v0.x * n0; a0.y += v0.y * n0; a0.z += v0.z * n0; a0.w += v0.w * n0;
        a1.x += v1.x * n1; a1.y += v1.y * n1; a1.z += v1.z * n1; a1.w += v1.w * n1;
    }
    if (p < p1) {
        int   s0 = csr_src[p];
        float n0 = csr_nrm[p];
        float4 v0 = ((const float4*)&xw[(size_t)s0 * H2])[d];
        a0.x += v0.x * n0; a0.y += v0.y * n0; a0.z += v0.z * n0; a0.w += v0.w * n0;
    }
    float4 bb = ((const float4*)b)[d];
    float4 o;
    o.x = fmaxf(a0.x + a1.x + bb.x, 0.f);
    o.y = fmaxf(a0.y + a1.y + bb.y, 0.f);
    o.z = fmaxf(a0.z + a1.z + bb.z, 0.f);
    o.w = fmaxf(a0.w + a1.w + bb.w, 0.f);
    ((float4*)&x2[(size_t)node * H2])[d] = o;
}

// ---------------- pooling ----------------
__global__ void cnt_accum(const int* __restrict__ batch, float* cnt) {
    int i = blockIdx.x * 256 + threadIdx.x;
    if (i < N_NODES) atomicAdd(&cnt[batch[i]], 1.0f);
}

__global__ void pool_accum(const int* __restrict__ batch, const float* __restrict__ x2,
                           float* __restrict__ pooled) {
    int d  = blockIdx.x * 256 + threadIdx.x;   // 0..1023
    int i0 = blockIdx.y * 64;
    float acc = 0.0f;
    int gprev = -1;
    for (int i = 0; i < 64; i++) {
        int node = i0 + i;
        if (node >= N_NODES) break;
        int g = batch[node];
        if (g != gprev) {
            if (gprev >= 0) atomicAdd(&pooled[gprev * H2 + d], acc);
            acc = 0.0f; gprev = g;
        }
        acc += x2[(size_t)node * H2 + d];
    }
    if (gprev >= 0) atomicAdd(&pooled[gprev * H2 + d], acc);
}

__global__ void pool_norm(float* pooled, const float* cnt) {
    int idx = blockIdx.x * 256 + threadIdx.x;
    if (idx < N_GRAPHS * H2) {
        int g = idx >> 10;
        pooled[idx] /= fmaxf(cnt[g], 1.0f);
    }
}

// ---------------- MLP head ----------------
__global__ __launch_bounds__(256) void head_gemm(const float* __restrict__ In,
                                                 const float* __restrict__ W,
                                                 float* __restrict__ Out, int K, int N) {
    __shared__ __align__(16) float As[16][256];
    int n  = blockIdx.x * 256 + threadIdx.x;
    int m0 = blockIdx.y * 16;
    int k0 = blockIdx.z * 256;
    for (int t = threadIdx.x; t < 16 * 256; t += 256) {
        int r = t >> 8, k = t & 255;
        As[r][k] = In[(size_t)(m0 + r) * K + k0 + k];
    }
    __syncthreads();
    float acc[16] = {};
    for (int k = 0; k < 256; k += 4) {
        float w0 = W[(size_t)(k0 + k + 0) * N + n];
        float w1 = W[(size_t)(k0 + k + 1) * N + n];
        float w2 = W[(size_t)(k0 + k + 2) * N + n];
        float w3 = W[(size_t)(k0 + k + 3) * N + n];
#pragma unroll
        for (int r = 0; r < 16; r++) {
            float4 a = *(const float4*)&As[r][k];
            acc[r] += a.x * w0 + a.y * w1 + a.z * w2 + a.w * w3;
        }
    }
    for (int r = 0; r < 16; r++)
        atomicAdd(&Out[(size_t)(m0 + r) * N + n], acc[r]);
}

__global__ void bias_relu_MN(float* __restrict__ x, const float* __restrict__ b,
                             int N, int total) {
    int idx = blockIdx.x * 256 + threadIdx.x;
    if (idx < total) {
        int d = idx & (N - 1);    // N is a power of two
        x[idx] = fmaxf(x[idx] + b[d], 0.0f);
    }
}

__global__ void head3(const float* __restrict__ h2, const float* __restrict__ oW,
                      const float* __restrict__ ob, float* __restrict__ out) {
    int tid = threadIdx.x;          // 128 threads: m = tid/2, c = tid&1
    if (tid >= 128) return;
    int m = tid >> 1, c = tid & 1;
    float acc = 0.0f;
    for (int k = 0; k < 512; k++) acc += h2[m * 512 + k] * oW[k * 2 + c];
    out[tid] = acc + ob[c];
}

// ---------------- host ----------------
extern "C" void kernel_launch(void* const* d_in, const int* in_sizes, int n_in,
                              void* d_out, int out_size, void* d_ws, size_t ws_size,
                              hipStream_t stream) {
    const int*   ids   = (const int*)d_in[0];
    const float* other = (const float*)d_in[1];
    const int*   ei    = (const int*)d_in[2];
    const int*   batch = (const int*)d_in[3];
    const float* emb   = (const float*)d_in[4];
    const float* W1    = (const float*)d_in[5];
    const float* b1    = (const float*)d_in[6];
    const float* W2    = (const float*)d_in[7];
    const float* b2    = (const float*)d_in[8];
    const float* hW1   = (const float*)d_in[9];
    const float* hb1   = (const float*)d_in[10];
    const float* hW2   = (const float*)d_in[11];
    const float* hb2   = (const float*)d_in[12];
    const float* oW    = (const float*)d_in[13];
    const float* ob    = (const float*)d_in[14];
    float* out = (float*)d_out;

    char* ws = (char*)d_ws;
    size_t off_b = 0;
    auto alloc = [&](size_t bytes) {
        size_t p = (off_b + 255) & ~(size_t)255;
        off_b = p + bytes;
        return p;
    };
    // total ~181 MB (chunked x1 keeps us under the R2-proven 254 MB; R3's 262 MB died)
    size_t o_dinv = alloc((size_t)N_NODES * 4);
    size_t o_indeg= alloc((size_t)(N_NODES + 1) * 4);
    size_t o_off  = alloc((size_t)(N_NODES + 1) * 4);
    size_t o_cur  = alloc((size_t)N_NODES * 4);
    size_t o_csrc = alloc((size_t)N_TOT_E * 4);
    size_t o_cnrm = alloc((size_t)N_TOT_E * 4);
    size_t o_xf   = alloc((size_t)N_NODES * IN_GNN * 4);
    size_t o_agg1 = alloc((size_t)N_NODES * IN_GNN * 4);
    size_t o_x1h  = alloc((size_t)CHUNK0 * H1 * 2);      // chunk-local bf16 hi
    size_t o_x1l  = alloc((size_t)CHUNK0 * H1 * 2);      // chunk-local bf16 lo
    size_t o_w2h  = alloc((size_t)H2 * H1 * 2);          // W2^T hi bf16 [1024][2048]
    size_t o_w2l  = alloc((size_t)H2 * H1 * 2);
    size_t o_xw2  = alloc((size_t)N_NODES * H2 * 4);
    size_t o_pool = alloc((size_t)N_GRAPHS * H2 * 4);
    size_t o_cnt  = alloc((size_t)N_GRAPHS * 4);
    size_t o_h1   = alloc((size_t)N_GRAPHS * 1024 * 4);
    size_t o_h2   = alloc((size_t)N_GRAPHS * 512 * 4);

    float* dinv = (float*)(ws + o_dinv);
    int*   indeg= (int*)(ws + o_indeg);
    int*   offs = (int*)(ws + o_off);
    int*   cur  = (int*)(ws + o_cur);
    int*   csrc = (int*)(ws + o_csrc);
    float* cnrm = (float*)(ws + o_cnrm);
    float* xf   = (float*)(ws + o_xf);
    float* agg1 = (float*)(ws + o_agg1);
    u16*   x1h  = (u16*)(ws + o_x1h);
    u16*   x1l  = (u16*)(ws + o_x1l);
    u16*   w2h  = (u16*)(ws + o_w2h);
    u16*   w2l  = (u16*)(ws + o_w2l);
    float* xw2  = (float*)(ws + o_xw2);
    // x2 aliases the x1h+x1l region (82.8 MB contiguous >= 80 MB needed; both dead then)
    float* x2   = (float*)(ws + o_x1h);
    float* pooled = (float*)(ws + o_pool);
    float* cnt  = (float*)(ws + o_cnt);
    float* h1   = (float*)(ws + o_h1);
    float* h2   = (float*)(ws + o_h2);

    // indegree (int); self loop = init 1; dinv = rsqrt(deg)
    fill_i32<<<(N_NODES + 255) / 256, 256, 0, stream>>>(indeg, 1, N_NODES);
    deg_accum<<<(N_EDGES + 255) / 256, 256, 0, stream>>>(ei, indeg);
    deg_to_dinv<<<(N_NODES + 255) / 256, 256, 0, stream>>>(indeg, dinv);

    // CSR
    scan_offsets<<<1, 1024, 0, stream>>>(indeg, offs, cur);
    csr_fill<<<(N_TOT_E + 255) / 256, 256, 0, stream>>>(ei, dinv, cur, csrc, cnrm);

    // node features + layer-1 aggregation (full graph)
    build_xfeat<<<(N_NODES * IN_GNN + 255) / 256, 256, 0, stream>>>(ids, other, emb, xf);
    agg_csr_36<<<(N_NODES * IN_GNN + 255) / 256, 256, 0, stream>>>(offs, csrc, cnrm, xf, agg1);

    // W2 -> transposed hi/lo bf16 (once)
    conv_w2<<<dim3(H1 / 32, H2 / 32), 256, 0, stream>>>(W2, w2h, w2l);

    // layers 1+2 GEMMs in two M-chunks to bound workspace
    {
        const int c0 = CHUNK0, c1 = N_NODES - CHUNK0;   // 10112, 9888
        // chunk 0
        gemm1_relu<<<dim3(H1 / 256, c0 / 32), 256, 0, stream>>>(agg1, W1, b1, x1h, x1l, 0, c0);
        gemm2_mfma<<<dim3(H2 / 128, c0 / 128), 256, 0, stream>>>(x1h, x1l, w2h, w2l, xw2, 0, c0);
        // chunk 1 (stream order guarantees chunk-0 gemm2 finished reading x1h/x1l)
        gemm1_relu<<<dim3(H1 / 256, c1 / 32), 256, 0, stream>>>(agg1, W1, b1, x1h, x1l, c0, c1);
        gemm2_mfma<<<dim3(H2 / 128, (c1 + 127) / 128), 256, 0, stream>>>(x1h, x1l, w2h, w2l, xw2, c0, c1);
    }

    // layer-2 aggregation with bias+relu fused (x2 overwrites dead x1h/x1l region)
    agg_csr_1024<<<N_NODES, 256, 0, stream>>>(offs, csrc, cnrm, xw2, b2, x2);

    // mean pool
    hipMemsetAsync(pooled, 0, (size_t)N_GRAPHS * H2 * 4, stream);
    hipMemsetAsync(cnt, 0, (size_t)N_GRAPHS * 4, stream);
    cnt_accum<<<(N_NODES + 255) / 256, 256, 0, stream>>>(batch, cnt);
    pool_accum<<<dim3(H2 / 256, (N_NODES + 63) / 64), 256, 0, stream>>>(batch, x2, pooled);
    pool_norm<<<(N_GRAPHS * H2 + 255) / 256, 256, 0, stream>>>(pooled, cnt);

    // head
    hipMemsetAsync(h1, 0, (size_t)N_GRAPHS * 1024 * 4, stream);
    head_gemm<<<dim3(1024 / 256, 4, 1024 / 256), 256, 0, stream>>>(pooled, hW1, h1, 1024, 1024);
    bias_relu_MN<<<(N_GRAPHS * 1024 + 255) / 256, 256, 0, stream>>>(h1, hb1, 1024, N_GRAPHS * 1024);

    hipMemsetAsync(h2, 0, (size_t)N_GRAPHS * 512 * 4, stream);
    head_gemm<<<dim3(512 / 256, 4, 1024 / 256), 256, 0, stream>>>(h1, hW2, h2, 1024, 512);
    bias_relu_MN<<<(N_GRAPHS * 512 + 255) / 256, 256, 0, stream>>>(h2, hb2, 512, N_GRAPHS * 512);

    head3<<<1, 128, 0, stream>>>(h2, oW, ob, out);
}

// Round 6
// 935.758 us; speedup vs baseline: 6.7072x; 1.1413x over previous
//
#include <hip/hip_runtime.h>
#include <hip/hip_bf16.h>

#define N_NODES  20000
#define N_EDGES  160000
#define N_TOT_E  180000   // edges + self loops
#define N_GRAPHS 64
#define EMBED_DIM 32
#define IN_GNN   36
#define K1PAD    64       // gemm1 K padded for MFMA
#define H1       2048
#define H2       1024
#define CHUNK0   10112    // 79 * 128; chunk1 = 9888 = N_NODES - CHUNK0

typedef unsigned short u16;
typedef short bf16x8 __attribute__((ext_vector_type(8)));
typedef float f32x4  __attribute__((ext_vector_type(4)));

__device__ inline u16 f32_to_bf16(float f) {
    union { float f; unsigned u; } v; v.f = f;
    unsigned lsb = (v.u >> 16) & 1u;
    return (u16)((v.u + 0x7fffu + lsb) >> 16);
}
__device__ inline float bf16_to_f32(u16 h) {
    union { unsigned u; float f; } v; v.u = ((unsigned)h) << 16;
    return v.f;
}

// ---------------- small utility kernels ----------------

__global__ void fill_i32(int* p, int v, int n) {
    int i = blockIdx.x * 256 + threadIdx.x;
    if (i < n) p[i] = v;
}

__global__ void deg_accum(const int* __restrict__ ei, int* indeg) {
    int e = blockIdx.x * 256 + threadIdx.x;
    if (e < N_EDGES) atomicAdd(&indeg[ei[N_EDGES + e]], 1);
}

__global__ void deg_to_dinv(const int* __restrict__ indeg, float* __restrict__ d) {
    int i = blockIdx.x * 256 + threadIdx.x;
    if (i < N_NODES) d[i] = rsqrtf((float)indeg[i]);   // deg >= 1 (self loop)
}

__global__ void build_xfeat(const int* __restrict__ ids, const float* __restrict__ other,
                            const float* __restrict__ emb, float* __restrict__ xf) {
    int idx = blockIdx.x * 256 + threadIdx.x;   // node*36 + d
    if (idx >= N_NODES * IN_GNN) return;
    int i = idx / IN_GNN;
    int d = idx - i * IN_GNN;
    float v = (d < EMBED_DIM) ? emb[(size_t)ids[i] * EMBED_DIM + d]
                              : other[i * 4 + (d - EMBED_DIM)];
    xf[idx] = v;
}

// ---------------- CSR build ----------------
__global__ __launch_bounds__(1024) void scan_offsets(const int* __restrict__ indeg,
                                                     int* __restrict__ off,
                                                     int* __restrict__ cursor) {
    __shared__ int buf[1024];
    __shared__ int base_s;
    int tid = threadIdx.x;
    if (tid == 0) base_s = 0;
    __syncthreads();
    for (int start = 0; start < N_NODES; start += 1024) {
        int i = start + tid;
        int v = (i < N_NODES) ? indeg[i] : 0;
        buf[tid] = v;
        __syncthreads();
        for (int s = 1; s < 1024; s <<= 1) {
            int t = (tid >= s) ? buf[tid - s] : 0;
            __syncthreads();
            buf[tid] += t;
            __syncthreads();
        }
        int incl = buf[tid];
        int excl = incl - v;
        int base = base_s;
        if (i < N_NODES) {
            int o = base + excl;
            off[i] = o;
            cursor[i] = o;
        }
        __syncthreads();
        if (tid == 1023) base_s = base + incl;
        __syncthreads();
    }
    if (tid == 0) off[N_NODES] = N_TOT_E;
}

__global__ void csr_fill(const int* __restrict__ ei, const float* __restrict__ dinv,
                         int* __restrict__ cursor,
                         int* __restrict__ csr_src, float* __restrict__ csr_nrm) {
    int e = blockIdx.x * 256 + threadIdx.x;
    if (e >= N_TOT_E) return;
    int s, t;
    if (e < N_EDGES) { s = ei[e]; t = ei[N_EDGES + e]; }
    else             { s = t = e - N_EDGES; }
    int pos = atomicAdd(&cursor[t], 1);
    csr_src[pos] = s;
    csr_nrm[pos] = dinv[s] * dinv[t];
}

// ---------------- layer-1 aggregation via CSR gather -> hi/lo bf16, [node][64] padded
__global__ void agg_csr_36(const int* __restrict__ off, const int* __restrict__ csr_src,
                           const float* __restrict__ csr_nrm,
                           const float* __restrict__ xf,
                           u16* __restrict__ aggh, u16* __restrict__ aggl) {
    int idx = blockIdx.x * 256 + threadIdx.x;   // node*64 + d
    if (idx >= N_NODES * K1PAD) return;
    int node = idx >> 6;
    int d = idx & 63;
    u16 hi = 0, lo = 0;
    if (d < IN_GNN) {
        int p0 = off[node], p1 = off[node + 1];
        float acc = 0.0f;
        for (int p = p0; p < p1; p++)
            acc += xf[csr_src[p] * IN_GNN + d] * csr_nrm[p];
        hi = f32_to_bf16(acc);
        lo = f32_to_bf16(acc - bf16_to_f32(hi));
    }
    aggh[idx] = hi;
    aggl[idx] = lo;
}

// ---------------- W1 [36,2048] f32 -> transposed hi/lo bf16 [2048][64] (padded) ----
__global__ void conv_w1(const float* __restrict__ W,
                        u16* __restrict__ Bh, u16* __restrict__ Bl) {
    int idx = blockIdx.x * 256 + threadIdx.x;   // n*64 + k
    if (idx >= H1 * K1PAD) return;
    int n = idx >> 6;
    int k = idx & 63;
    u16 hi = 0, lo = 0;
    if (k < IN_GNN) {
        float v = W[(size_t)k * H1 + n];
        hi = f32_to_bf16(v);
        lo = f32_to_bf16(v - bf16_to_f32(hi));
    }
    Bh[idx] = hi;
    Bl[idx] = lo;
}

// ---------------- W2 [2048,1024] f32 -> transposed hi/lo bf16 [1024,2048] ----------
__global__ __launch_bounds__(256) void conv_w2(const float* __restrict__ W,
                                               u16* __restrict__ Bh,
                                               u16* __restrict__ Bl) {
    __shared__ float t[32][33];
    int bk = blockIdx.x * 32;   // k block
    int bn = blockIdx.y * 32;   // n block
    int tx = threadIdx.x & 31, ty = threadIdx.x >> 5;   // 32 x 8
#pragma unroll
    for (int i = 0; i < 32; i += 8)
        t[ty + i][tx] = W[(size_t)(bk + ty + i) * H2 + bn + tx];
    __syncthreads();
#pragma unroll
    for (int i = 0; i < 32; i += 8) {
        float v = t[tx][ty + i];            // = W[bk+tx][bn+ty+i]
        u16 hi = f32_to_bf16(v);
        u16 lo = f32_to_bf16(v - bf16_to_f32(hi));
        size_t o = (size_t)(bn + ty + i) * H1 + bk + tx;   // Bt[n][k]
        Bh[o] = hi;
        Bl[o] = lo;
    }
}

// ---------------- GEMM1 via bf16 MFMA: agg[rows,64p] @ W1t[2048,64p] + b1, relu ----
// -> x1 hi/lo bf16 (chunk-local). 128x128 tile, single K stage (2 k-steps), 4 waves.
__global__ __launch_bounds__(256) void gemm1_mfma(const u16* __restrict__ Ah,
                                                  const u16* __restrict__ Al,
                                                  const u16* __restrict__ Bh,
                                                  const u16* __restrict__ Bl,
                                                  const float* __restrict__ bias,
                                                  u16* __restrict__ Xh,
                                                  u16* __restrict__ Xl,
                                                  int rowbase, int nrows) {
    __shared__ u16 lds[4][128 * K1PAD];   // 16 KB each, 64 KB total
    const int tid  = threadIdx.x;
    const int wid  = tid >> 6;
    const int lane = tid & 63;
    const int wr   = wid >> 1, wc = wid & 1;
    const int row0 = blockIdx.y * 128;          // chunk-local
    const int col0 = blockIdx.x * 128;          // over H1=2048

    const u16* gbase;
    int rbase; bool isA;
    if      (wid == 0) { gbase = Ah; rbase = row0; isA = true; }
    else if (wid == 1) { gbase = Al; rbase = row0; isA = true; }
    else if (wid == 2) { gbase = Bh; rbase = col0; isA = false; }
    else               { gbase = Bl; rbase = col0; isA = false; }
    u16* myl = lds[wid];
    // 16 iters x (64 lanes x 16B) = 128 rows x 64 k x 2B; linear dest = lane*16B
    const int r_l  = lane >> 3;        // 0..7 row within 8-row group
    const int ks_l = (lane & 7) * 8;   // k offset
#pragma unroll
    for (int i = 0; i < 16; i++) {
        int r = rbase + i * 8 + r_l;
        if (isA) { int g = rowbase + ((r > nrows - 1) ? (nrows - 1) : r);
                   r = g; }            // clamp + global row for A
        const u16* g = gbase + (size_t)r * K1PAD + ks_l;
        __builtin_amdgcn_global_load_lds(
            (const __attribute__((address_space(1))) void*)g,
            (__attribute__((address_space(3))) void*)(myl + i * 512),
            16, 0, 0);
    }
    __syncthreads();   // drains vmcnt; all 4 tiles visible

    f32x4 acc[4][4] = {};
#pragma unroll
    for (int ks = 0; ks < 2; ks++) {
        bf16x8 afh[4], afl[4];
#pragma unroll
        for (int mi = 0; mi < 4; mi++) {
            int r   = wr * 64 + mi * 16 + (lane & 15);
            int off = r * K1PAD + ks * 32 + (lane >> 4) * 8;
            afh[mi] = *(const bf16x8*)&lds[0][off];
            afl[mi] = *(const bf16x8*)&lds[1][off];
        }
#pragma unroll
        for (int ni = 0; ni < 4; ni++) {
            int c   = wc * 64 + ni * 16 + (lane & 15);
            int off = c * K1PAD + ks * 32 + (lane >> 4) * 8;
            bf16x8 bfh = *(const bf16x8*)&lds[2][off];
            bf16x8 bfl = *(const bf16x8*)&lds[3][off];
#pragma unroll
            for (int mi = 0; mi < 4; mi++) {
                acc[mi][ni] = __builtin_amdgcn_mfma_f32_16x16x32_bf16(afh[mi], bfh, acc[mi][ni], 0, 0, 0);
                acc[mi][ni] = __builtin_amdgcn_mfma_f32_16x16x32_bf16(afh[mi], bfl, acc[mi][ni], 0, 0, 0);
                acc[mi][ni] = __builtin_amdgcn_mfma_f32_16x16x32_bf16(afl[mi], bfh, acc[mi][ni], 0, 0, 0);
            }
        }
    }

    // epilogue: bias + relu + hi/lo split; C/D: col=lane&15, row=(lane>>4)*4+j
#pragma unroll
    for (int ni = 0; ni < 4; ni++) {
        int col = col0 + wc * 64 + ni * 16 + (lane & 15);
        float bb = bias[col];
#pragma unroll
        for (int mi = 0; mi < 4; mi++) {
#pragma unroll
            for (int j = 0; j < 4; j++) {
                int lr = row0 + wr * 64 + mi * 16 + (lane >> 4) * 4 + j;
                if (lr < nrows) {
                    float v = fmaxf(acc[mi][ni][j] + bb, 0.0f);
                    u16 hi = f32_to_bf16(v);
                    Xh[(size_t)lr * H1 + col] = hi;
                    Xl[(size_t)lr * H1 + col] = f32_to_bf16(v - bf16_to_f32(hi));
                }
            }
        }
    }
}

// ---------------- GEMM2 via bf16 MFMA (hi/lo split, 3 products) -----------------
// C[rowbase+lr, 1024] = (Ah+Al)[lr,2048] @ (Bh+Bl)^T-stored[1024,2048]
// 128x128 tile, BK=32, 4 waves. XCD-aware remap keeps one A row-panel on one XCD.
__global__ __launch_bounds__(256) void gemm2_mfma(const u16* __restrict__ Ah,
                                                  const u16* __restrict__ Al,
                                                  const u16* __restrict__ Bh,
                                                  const u16* __restrict__ Bl,
                                                  float* __restrict__ C,
                                                  int rowbase, int nrows) {
    __shared__ u16 lds[4][128 * 32];   // Ah, Al, Bh, Bl tiles: 8 KB each
    const int tid  = threadIdx.x;
    const int wid  = tid >> 6;
    const int lane = tid & 63;
    const int wr   = wid >> 1, wc = wid & 1;

    // ---- XCD-aware bijective remap (gridDim.x == 8) ----
    int NB = (int)(gridDim.x * gridDim.y);
    int b  = (int)(blockIdx.y * gridDim.x + blockIdx.x);
    int lin = b;
    if ((NB & 7) == 0) {
        int xcd = b & 7, j = b >> 3;      // round-robin slot -> contiguous run
        lin = xcd * (NB >> 3) + j;
    }
    const int col0 = (lin & 7) * 128;
    const int row0 = (lin >> 3) * 128;    // chunk-local

    const u16* gbase;
    int rbase;
    if      (wid == 0) { gbase = Ah; rbase = row0; }
    else if (wid == 1) { gbase = Al; rbase = row0; }
    else if (wid == 2) { gbase = Bh; rbase = col0; }
    else               { gbase = Bl; rbase = col0; }
    u16* myl = lds[wid];
    const int r_l  = lane >> 2;        // 0..15
    const int ks_l = (lane & 3) * 8;   // 0,8,16,24  (lds dest byte = lane*16, linear)

    int rows[8];
#pragma unroll
    for (int i = 0; i < 8; i++) {
        int r = rbase + i * 16 + r_l;
        if (wid < 2 && r > nrows - 1) r = nrows - 1;   // clamp A-side reads to chunk
        rows[i] = r;
    }

    f32x4 acc[4][4] = {};

    for (int kt = 0; kt < H1 / 32; ++kt) {
        int k0 = kt * 32;
        __syncthreads();   // previous compute done before overwrite
#pragma unroll
        for (int i = 0; i < 8; i++) {
            const u16* g = gbase + (size_t)rows[i] * H1 + k0 + ks_l;
            __builtin_amdgcn_global_load_lds(
                (const __attribute__((address_space(1))) void*)g,
                (__attribute__((address_space(3))) void*)(myl + i * 512),
                16, 0, 0);
        }
        __syncthreads();   // compiler drains vmcnt before barrier

        bf16x8 afh[4], afl[4];
#pragma unroll
        for (int mi = 0; mi < 4; mi++) {
            int r   = wr * 64 + mi * 16 + (lane & 15);
            int off = r * 32 + (lane >> 4) * 8;
            afh[mi] = *(const bf16x8*)&lds[0][off];
            afl[mi] = *(const bf16x8*)&lds[1][off];
        }
#pragma unroll
        for (int ni = 0; ni < 4; ni++) {
            int c   = wc * 64 + ni * 16 + (lane & 15);
            int off = c * 32 + (lane >> 4) * 8;
            bf16x8 bfh = *(const bf16x8*)&lds[2][off];
            bf16x8 bfl = *(const bf16x8*)&lds[3][off];
#pragma unroll
            for (int mi = 0; mi < 4; mi++) {
                acc[mi][ni] = __builtin_amdgcn_mfma_f32_16x16x32_bf16(afh[mi], bfh, acc[mi][ni], 0, 0, 0);
                acc[mi][ni] = __builtin_amdgcn_mfma_f32_16x16x32_bf16(afh[mi], bfl, acc[mi][ni], 0, 0, 0);
                acc[mi][ni] = __builtin_amdgcn_mfma_f32_16x16x32_bf16(afl[mi], bfh, acc[mi][ni], 0, 0, 0);
            }
        }
    }

    // C/D layout: col = lane&15, row = (lane>>4)*4 + j  [m89/m91 verified]
#pragma unroll
    for (int mi = 0; mi < 4; mi++) {
#pragma unroll
        for (int ni = 0; ni < 4; ni++) {
            int col = col0 + wc * 64 + ni * 16 + (lane & 15);
#pragma unroll
            for (int j = 0; j < 4; j++) {
                int lr = row0 + wr * 64 + mi * 16 + (lane >> 4) * 4 + j;
                if (lr < nrows) C[(size_t)(rowbase + lr) * H2 + col] = acc[mi][ni][j];
            }
        }
    }
}

// ---------------- layer-2 aggregation via CSR gather (1024-dim), bias+relu fused ----
__global__ __launch_bounds__(256) void agg_csr_1024(const int* __restrict__ off,
                                                    const int* __restrict__ csr_src,
                                                    const float* __restrict__ csr_nrm,
                                                    const float* __restrict__ xw,
                                                    const float* __restrict__ b,
                                                    float* __restrict__ x2) {
    int node = blockIdx.x;
    int p0 = off[node], p1 = off[node + 1];
    int d = threadIdx.x;             // float4 lane: 256 x 4 = 1024 dims
    float4 a0 = make_float4(0.f, 0.f, 0.f, 0.f);
    float4 a1 = make_float4(0.f, 0.f, 0.f, 0.f);
    int p = p0;
    for (; p + 1 < p1; p += 2) {
        int   s0 = csr_src[p],     s1 = csr_src[p + 1];
        float n0 = csr_nrm[p],     n1 = csr_nrm[p + 1];
        float4 v0 = ((const float4*)&xw[(size_t)s0 * H2])[d];
        float4 v1 = ((const float4*)&xw[(size_t)s1 * H2])[d];
        a0.x += v0.x * n0; a0.y += v0.y * n0; a0.z += v0.z * n0; a0.w += v0.w * n0;
        a1.x += v1.x * n1; a1.y += v1.y * n1; a1.z += v1.z * n1; a1.w += v1.w * n1;
    }
    if (p < p1) {
        int   s0 = csr_src[p];
        float n0 = csr_nrm[p];
        float4 v0 = ((const float4*)&xw[(size_t)s0 * H2])[d];
        a0.x += v0.x * n0; a0.y += v0.y * n0; a0.z += v0.z * n0; a0.w += v0.w * n0;
    }
    float4 bb = ((const float4*)b)[d];
    float4 o;
    o.x = fmaxf(a0.x + a1.x + bb.x, 0.f);
    o.y = fmaxf(a0.y + a1.y + bb.y, 0.f);
    o.z = fmaxf(a0.z + a1.z + bb.z, 0.f);
    o.w = fmaxf(a0.w + a1.w + bb.w, 0.f);
    ((float4*)&x2[(size_t)node * H2])[d] = o;
}

// ---------------- pooling ----------------
__global__ void cnt_accum(const int* __restrict__ batch, float* cnt) {
    int i = blockIdx.x * 256 + threadIdx.x;
    if (i < N_NODES) atomicAdd(&cnt[batch[i]], 1.0f);
}

__global__ void pool_accum(const int* __restrict__ batch, const float* __restrict__ x2,
                           float* __restrict__ pooled) {
    int d  = blockIdx.x * 256 + threadIdx.x;   // 0..1023
    int i0 = blockIdx.y * 64;
    float acc = 0.0f;
    int gprev = -1;
    for (int i = 0; i < 64; i++) {
        int node = i0 + i;
        if (node >= N_NODES) break;
        int g = batch[node];
        if (g != gprev) {
            if (gprev >= 0) atomicAdd(&pooled[gprev * H2 + d], acc);
            acc = 0.0f; gprev = g;
        }
        acc += x2[(size_t)node * H2 + d];
    }
    if (gprev >= 0) atomicAdd(&pooled[gprev * H2 + d], acc);
}

__global__ void pool_norm(float* pooled, const float* cnt) {
    int idx = blockIdx.x * 256 + threadIdx.x;
    if (idx < N_GRAPHS * H2) {
        int g = idx >> 10;
        pooled[idx] /= fmaxf(cnt[g], 1.0f);
    }
}

// ---------------- MLP head ----------------
__global__ __launch_bounds__(256) void head_gemm(const float* __restrict__ In,
                                                 const float* __restrict__ W,
                                                 float* __restrict__ Out, int K, int N) {
    __shared__ __align__(16) float As[16][256];
    int n  = blockIdx.x * 256 + threadIdx.x;
    int m0 = blockIdx.y * 16;
    int k0 = blockIdx.z * 256;
    for (int t = threadIdx.x; t < 16 * 256; t += 256) {
        int r = t >> 8, k = t & 255;
        As[r][k] = In[(size_t)(m0 + r) * K + k0 + k];
    }
    __syncthreads();
    float acc[16] = {};
    for (int k = 0; k < 256; k += 4) {
        float w0 = W[(size_t)(k0 + k + 0) * N + n];
        float w1 = W[(size_t)(k0 + k + 1) * N + n];
        float w2 = W[(size_t)(k0 + k + 2) * N + n];
        float w3 = W[(size_t)(k0 + k + 3) * N + n];
#pragma unroll
        for (int r = 0; r < 16; r++) {
            float4 a = *(const float4*)&As[r][k];
            acc[r] += a.x * w0 + a.y * w1 + a.z * w2 + a.w * w3;
        }
    }
    for (int r = 0; r < 16; r++)
        atomicAdd(&Out[(size_t)(m0 + r) * N + n], acc[r]);
}

__global__ void bias_relu_MN(float* __restrict__ x, const float* __restrict__ b,
                             int N, int total) {
    int idx = blockIdx.x * 256 + threadIdx.x;
    if (idx < total) {
        int d = idx & (N - 1);    // N is a power of two
        x[idx] = fmaxf(x[idx] + b[d], 0.0f);
    }
}

__global__ void head3(const float* __restrict__ h2, const float* __restrict__ oW,
                      const float* __restrict__ ob, float* __restrict__ out) {
    int tid = threadIdx.x;          // 128 threads: m = tid/2, c = tid&1
    if (tid >= 128) return;
    int m = tid >> 1, c = tid & 1;
    float acc = 0.0f;
    for (int k = 0; k < 512; k++) acc += h2[m * 512 + k] * oW[k * 2 + c];
    out[tid] = acc + ob[c];
}

// ---------------- host ----------------
extern "C" void kernel_launch(void* const* d_in, const int* in_sizes, int n_in,
                              void* d_out, int out_size, void* d_ws, size_t ws_size,
                              hipStream_t stream) {
    const int*   ids   = (const int*)d_in[0];
    const float* other = (const float*)d_in[1];
    const int*   ei    = (const int*)d_in[2];
    const int*   batch = (const int*)d_in[3];
    const float* emb   = (const float*)d_in[4];
    const float* W1    = (const float*)d_in[5];
    const float* b1    = (const float*)d_in[6];
    const float* W2    = (const float*)d_in[7];
    const float* b2    = (const float*)d_in[8];
    const float* hW1   = (const float*)d_in[9];
    const float* hb1   = (const float*)d_in[10];
    const float* hW2   = (const float*)d_in[11];
    const float* hb2   = (const float*)d_in[12];
    const float* oW    = (const float*)d_in[13];
    const float* ob    = (const float*)d_in[14];
    float* out = (float*)d_out;

    char* ws = (char*)d_ws;
    size_t off_b = 0;
    auto alloc = [&](size_t bytes) {
        size_t p = (off_b + 255) & ~(size_t)255;
        off_b = p + bytes;
        return p;
    };
    // total ~186 MB (R2-proven budget 254 MB; R3's 262 MB died)
    size_t o_dinv = alloc((size_t)N_NODES * 4);
    size_t o_indeg= alloc((size_t)(N_NODES + 1) * 4);
    size_t o_off  = alloc((size_t)(N_NODES + 1) * 4);
    size_t o_cur  = alloc((size_t)N_NODES * 4);
    size_t o_csrc = alloc((size_t)N_TOT_E * 4);
    size_t o_cnrm = alloc((size_t)N_TOT_E * 4);
    size_t o_xf   = alloc((size_t)N_NODES * IN_GNN * 4);
    size_t o_aggh = alloc((size_t)N_NODES * K1PAD * 2);  // bf16 hi, padded
    size_t o_aggl = alloc((size_t)N_NODES * K1PAD * 2);  // bf16 lo
    size_t o_w1h  = alloc((size_t)H1 * K1PAD * 2);       // W1^T hi bf16 [2048][64]
    size_t o_w1l  = alloc((size_t)H1 * K1PAD * 2);
    size_t o_x1h  = alloc((size_t)CHUNK0 * H1 * 2);      // chunk-local bf16 hi
    size_t o_x1l  = alloc((size_t)CHUNK0 * H1 * 2);      // chunk-local bf16 lo
    size_t o_w2h  = alloc((size_t)H2 * H1 * 2);          // W2^T hi bf16 [1024][2048]
    size_t o_w2l  = alloc((size_t)H2 * H1 * 2);
    size_t o_xw2  = alloc((size_t)N_NODES * H2 * 4);
    size_t o_pool = alloc((size_t)N_GRAPHS * H2 * 4);
    size_t o_cnt  = alloc((size_t)N_GRAPHS * 4);
    size_t o_h1   = alloc((size_t)N_GRAPHS * 1024 * 4);
    size_t o_h2   = alloc((size_t)N_GRAPHS * 512 * 4);

    float* dinv = (float*)(ws + o_dinv);
    int*   indeg= (int*)(ws + o_indeg);
    int*   offs = (int*)(ws + o_off);
    int*   cur  = (int*)(ws + o_cur);
    int*   csrc = (int*)(ws + o_csrc);
    float* cnrm = (float*)(ws + o_cnrm);
    float* xf   = (float*)(ws + o_xf);
    u16*   aggh = (u16*)(ws + o_aggh);
    u16*   aggl = (u16*)(ws + o_aggl);
    u16*   w1h  = (u16*)(ws + o_w1h);
    u16*   w1l  = (u16*)(ws + o_w1l);
    u16*   x1h  = (u16*)(ws + o_x1h);
    u16*   x1l  = (u16*)(ws + o_x1l);
    u16*   w2h  = (u16*)(ws + o_w2h);
    u16*   w2l  = (u16*)(ws + o_w2l);
    float* xw2  = (float*)(ws + o_xw2);
    // x2 aliases the x1h+x1l region (82.8 MB contiguous >= 80 MB; both dead then)
    float* x2   = (float*)(ws + o_x1h);
    float* pooled = (float*)(ws + o_pool);
    float* cnt  = (float*)(ws + o_cnt);
    float* h1   = (float*)(ws + o_h1);
    float* h2   = (float*)(ws + o_h2);

    // indegree (int); self loop = init 1; dinv = rsqrt(deg)
    fill_i32<<<(N_NODES + 255) / 256, 256, 0, stream>>>(indeg, 1, N_NODES);
    deg_accum<<<(N_EDGES + 255) / 256, 256, 0, stream>>>(ei, indeg);
    deg_to_dinv<<<(N_NODES + 255) / 256, 256, 0, stream>>>(indeg, dinv);

    // CSR
    scan_offsets<<<1, 1024, 0, stream>>>(indeg, offs, cur);
    csr_fill<<<(N_TOT_E + 255) / 256, 256, 0, stream>>>(ei, dinv, cur, csrc, cnrm);

    // node features + layer-1 aggregation (full graph) -> padded hi/lo bf16
    build_xfeat<<<(N_NODES * IN_GNN + 255) / 256, 256, 0, stream>>>(ids, other, emb, xf);
    agg_csr_36<<<(N_NODES * K1PAD + 255) / 256, 256, 0, stream>>>(offs, csrc, cnrm, xf, aggh, aggl);

    // weights -> transposed hi/lo bf16 (once)
    conv_w1<<<(H1 * K1PAD + 255) / 256, 256, 0, stream>>>(W1, w1h, w1l);
    conv_w2<<<dim3(H1 / 32, H2 / 32), 256, 0, stream>>>(W2, w2h, w2l);

    // layers 1+2 GEMMs in two M-chunks to bound workspace
    {
        const int c0 = CHUNK0, c1 = N_NODES - CHUNK0;   // 10112, 9888
        // chunk 0
        gemm1_mfma<<<dim3(H1 / 128, c0 / 128), 256, 0, stream>>>(aggh, aggl, w1h, w1l, b1, x1h, x1l, 0, c0);
        gemm2_mfma<<<dim3(H2 / 128, c0 / 128), 256, 0, stream>>>(x1h, x1l, w2h, w2l, xw2, 0, c0);
        // chunk 1 (stream order guarantees chunk-0 gemm2 finished reading x1h/x1l)
        gemm1_mfma<<<dim3(H1 / 128, (c1 + 127) / 128), 256, 0, stream>>>(aggh, aggl, w1h, w1l, b1, x1h, x1l, c0, c1);
        gemm2_mfma<<<dim3(H2 / 128, (c1 + 127) / 128), 256, 0, stream>>>(x1h, x1l, w2h, w2l, xw2, c0, c1);
    }

    // layer-2 aggregation with bias+relu fused (x2 overwrites dead x1h/x1l region)
    agg_csr_1024<<<N_NODES, 256, 0, stream>>>(offs, csrc, cnrm, xw2, b2, x2);

    // mean pool
    hipMemsetAsync(pooled, 0, (size_t)N_GRAPHS * H2 * 4, stream);
    hipMemsetAsync(cnt, 0, (size_t)N_GRAPHS * 4, stream);
    cnt_accum<<<(N_NODES + 255) / 256, 256, 0, stream>>>(batch, cnt);
    pool_accum<<<dim3(H2 / 256, (N_NODES + 63) / 64), 256, 0, stream>>>(batch, x2, pooled);
    pool_norm<<<(N_GRAPHS * H2 + 255) / 256, 256, 0, stream>>>(pooled, cnt);

    // head
    hipMemsetAsync(h1, 0, (size_t)N_GRAPHS * 1024 * 4, stream);
    head_gemm<<<dim3(1024 / 256, 4, 1024 / 256), 256, 0, stream>>>(pooled, hW1, h1, 1024, 1024);
    bias_relu_MN<<<(N_GRAPHS * 1024 + 255) / 256, 256, 0, stream>>>(h1, hb1, 1024, N_GRAPHS * 1024);

    hipMemsetAsync(h2, 0, (size_t)N_GRAPHS * 512 * 4, stream);
    head_gemm<<<dim3(512 / 256, 4, 1024 / 256), 256, 0, stream>>>(h1, hW2, h2, 1024, 512);
    bias_relu_MN<<<(N_GRAPHS * 512 + 255) / 256, 256, 0, stream>>>(h2, hb2, 512, N_GRAPHS * 512);

    head3<<<1, 128, 0, stream>>>(h2, oW, ob, out);
}